// Round 15
// baseline (467.198 us; speedup 1.0000x reference)
//
#include <hip/hip_runtime.h>
#include <math.h>

#define BB 4
#define CC 64
#define NN 4096
#define OO 64
#define KNN 32
#define CAND_MAX 192
#define EPS2 0.0625f

// ws layout (float offsets) — base footprint 23.66 MB; split path total
// 90.8 MB (R3/R9-proven). xh/xl ALIAS the hmax/hmin regions (disjoint
// lifetimes: xh/xl live k1->k2m; hmax/hmin live k3->k5).
#define XT_OFF    0u          // (B,N,C) fp32          1048576
#define SQ_OFF    1048576u    // (B,N) fp32             16384
#define P_OFF     1064960u    // (B,N,O)               1048576
#define BASE_OFF  2113536u    // (B,N,O)               1048576
#define HMAX_OFF  3162112u    // (B,N,O)               1048576  (k1-k2m: xh)
#define HMIN_OFF  4210688u    // (B,N,O)               1048576  (k1-k2m: xl)
#define STATS_OFF 5259264u    // 1024 x 128            131072
#define SCSH_OFF  5390336u    // 128
#define IDX_OFF   5390464u    // (B,N,K) int32         524288
// gap/i33 overlay the stats region (disjoint lifetimes: k2/k2f before k3)
#define GAP_OFF   5259264u    // (B*N) uint            16384
#define I33_OFF   5275648u    // (B*N) int              16384
// 32-bit screen keys (split path): one batch (N,N) uint = 67.1MB
#define KEYS_OFF  5914752u    // (N,N) uint32          16777216

typedef short bf16x8 __attribute__((ext_vector_type(8)));
typedef float f32x4 __attribute__((ext_vector_type(4)));

__device__ __forceinline__ float keyToFloat(unsigned int u) {
  unsigned int b = (u & 0x80000000u) ? (u & 0x7fffffffu) : ~u;
  return __uint_as_float(b);
}
__device__ __forceinline__ unsigned int floatToKey(float f) {
  unsigned int bb = __float_as_uint(f);
  return (bb & 0x80000000u) ? ~bb : (bb | 0x80000000u);
}
__device__ __forceinline__ unsigned short f2bf(float f) {
  unsigned u = __float_as_uint(f);
  unsigned r = ((u >> 16) & 1u) + 0x7fffu;  // RNE
  return (unsigned short)((u + r) >> 16);
}
__device__ __forceinline__ float bf2f(unsigned short h) {
  return __uint_as_float(((unsigned)h) << 16);
}
// load 8 floats at p, split into hi/lo bf16 fragments (fallback path only)
__device__ __forceinline__ void split8(const float* p, bf16x8& h, bf16x8& l) {
  float4 a = *(const float4*)p;
  float4 b = *(const float4*)(p + 4);
  float v[8] = {a.x, a.y, a.z, a.w, b.x, b.y, b.z, b.w};
#pragma unroll
  for (int e = 0; e < 8; ++e) {
    unsigned short hh = f2bf(v[e]);
    h[e] = (short)hh;
    l[e] = (short)f2bf(v[e] - bf2f(hh));
  }
}
// wave-wide sums via ballots — no DS-pipe ops
__device__ __forceinline__ int waveSum7(int local) {
  int s = 0;
#pragma unroll
  for (int b = 0; b < 7; ++b)
    s += (int)__popcll(__ballot((local >> b) & 1)) << b;
  return s;
}
__device__ __forceinline__ int waveSum2(int local) {
  int s = (int)__popcll(__ballot(local & 1));
  s += (int)__popcll(__ballot((local >> 1) & 1)) << 1;
  return s;
}

// ---------------- K1: transpose + sq + precomputed bf16 hi/lo split -------
__global__ __launch_bounds__(256) void k1_transpose_sq(
    const float* __restrict__ pts, float* __restrict__ xT, float* __restrict__ sqf,
    unsigned short* __restrict__ xh, unsigned short* __restrict__ xl) {
  __shared__ float tile[64 * 65];
  __shared__ double sqp[256];
  const int t = threadIdx.x, blk = blockIdx.x;
  const int b = blk >> 6, n0 = (blk & 63) << 6;
  const float* pb = pts + (size_t)b * CC * NN;
  const int j = t & 63, cg = t >> 6;
  double acc = 0.0;
#pragma unroll
  for (int i = 0; i < 16; ++i) {
    int c = cg * 16 + i;
    float v = pb[(size_t)c * NN + n0 + j];
    tile[c * 65 + j] = v;
    acc += (double)v * (double)v;
  }
  sqp[t] = acc;
  __syncthreads();
  const int c2 = t & 63, jg = t >> 6;
#pragma unroll
  for (int i = 0; i < 16; ++i) {
    int jj = jg * 16 + i;
    float vv = tile[c2 * 65 + jj];
    size_t xoff = ((size_t)b * NN + n0 + jj) * CC + c2;
    xT[xoff] = vv;
    unsigned short hh = f2bf(vv);
    xh[xoff] = hh;
    xl[xoff] = f2bf(vv - bf2f(hh));
  }
  if (t < 64)
    sqf[b * NN + n0 + t] = (float)(sqp[t] + sqp[64 + t] + sqp[128 + t] + sqp[192 + t]);
}

// ---------------- K2b: P = x.w2^T, base = x.(w1-w2)^T ---------------------
__global__ __launch_bounds__(256) void k2b_small_gemm(
    const float* __restrict__ xT, const float* __restrict__ W,
    float* __restrict__ P, float* __restrict__ base) {
  __shared__ float w2T[64 * 65];
  __shared__ float wdT[64 * 65];
  __shared__ float xbuf[4 * 64];
  const int t = threadIdx.x, blk = blockIdx.x;
  const int b = blk >> 6, n0 = (blk & 63) << 6;
#pragma unroll
  for (int i = 0; i < 16; ++i) {
    int e = i * 256 + t, o = e >> 6, c = e & 63;
    w2T[c * 65 + o] = W[o * 128 + 64 + c];
  }
  __syncthreads();
#pragma unroll
  for (int i = 0; i < 16; ++i) {
    int e = i * 256 + t, o = e >> 6, c = e & 63;
    wdT[c * 65 + o] = W[o * 128 + c] - w2T[c * 65 + o];
  }
  __syncthreads();
  const int w = t >> 6, lane = t & 63;
  for (int it = 0; it < 16; ++it) {
    int n = n0 + it * 4 + w;
    xbuf[t] = xT[((size_t)b * NN + n) * CC + lane];
    __syncthreads();
    float accP = 0.f, accB = 0.f;
#pragma unroll
    for (int c = 0; c < 64; ++c) {
      float xc = xbuf[w * 64 + c];
      accP = fmaf(xc, w2T[c * 65 + lane], accP);
      accB = fmaf(xc, wdT[c * 65 + lane], accB);
    }
    size_t off = ((size_t)b * NN + n) * OO + lane;
    P[off] = accP;
    base[off] = accB;
    __syncthreads();
  }
}

// ---------------- K2m: MFMA screen from precomputed bf16 split ------------
// (256,4): VGPR 80 <= 128-granule -> 4 blocks/CU co-residency, no spill.
__global__ __launch_bounds__(256, 4) void k2m_mfma_screen(
    const unsigned short* __restrict__ xhb, const unsigned short* __restrict__ xlb,
    const float* __restrict__ sqb, unsigned int* __restrict__ keys) {
  const int t = threadIdx.x, blk = blockIdx.x;
  const int stripe = blk >> 3;   // rows stripe*32..+31
  const int chunk = blk & 7;     // cols chunk*512..+511
  const int wid = t >> 6, l = t & 63;
  const int r0 = stripe * 32;
  const int cbase = chunk * 512 + wid * 128;
  const int i16 = l & 15, kb = l >> 4;

  bf16x8 ah[2][2], al[2][2];
#pragma unroll
  for (int rt = 0; rt < 2; ++rt) {
    size_t rb = (size_t)(r0 + rt * 16 + i16) * CC + kb * 8;
#pragma unroll
    for (int kc = 0; kc < 2; ++kc) {
      ah[rt][kc] = *(const bf16x8*)&xhb[rb + kc * 32];
      al[rt][kc] = *(const bf16x8*)&xlb[rb + kc * 32];
    }
  }
  float srow[2][4];
#pragma unroll
  for (int rt = 0; rt < 2; ++rt)
#pragma unroll
    for (int v = 0; v < 4; ++v)
      srow[rt][v] = sqb[r0 + rt * 16 + kb * 4 + v];

  for (int ct = 0; ct < 8; ++ct) {
    const int colg = cbase + ct * 16 + i16;
    bf16x8 bh[2], bl[2];
    size_t cb = (size_t)colg * CC + kb * 8;
#pragma unroll
    for (int kc = 0; kc < 2; ++kc) {
      bh[kc] = *(const bf16x8*)&xhb[cb + kc * 32];
      bl[kc] = *(const bf16x8*)&xlb[cb + kc * 32];
    }
    const float sqc = sqb[colg];
#pragma unroll
    for (int rt = 0; rt < 2; ++rt) {
      f32x4 acc = {0.f, 0.f, 0.f, 0.f};
#pragma unroll
      for (int kc = 0; kc < 2; ++kc) {
        acc = __builtin_amdgcn_mfma_f32_16x16x32_bf16(ah[rt][kc], bh[kc], acc, 0, 0, 0);
        acc = __builtin_amdgcn_mfma_f32_16x16x32_bf16(ah[rt][kc], bl[kc], acc, 0, 0, 0);
        acc = __builtin_amdgcn_mfma_f32_16x16x32_bf16(al[rt][kc], bh[kc], acc, 0, 0, 0);
      }
      const int rowb = r0 + rt * 16 + kb * 4;
#pragma unroll
      for (int v = 0; v < 4; ++v) {
        float d = 2.0f * acc[v] - srow[rt][v] - sqc;
        keys[(size_t)(rowb + v) * NN + colg] = floatToKey(d);
      }
    }
  }
}

// ---------------- K2sel: per-wave select, ballot-counted ------------------
// CHANGE vs R14: __launch_bounds__(256, 4). R14 measured occupancy 24.7%
// (2 blocks/CU, the (256,2) hint was the limiter) with VGPR=84 and LDS
// 5.6KB — both allow 4 blocks/CU (VGPR 128-granule). Grid is exactly 1024
// = 4/CU, so the whole k2sel grid becomes co-resident. No semantic change.
__global__ __launch_bounds__(256, 4) void k2sel(
    const unsigned int* __restrict__ keysb, const float* __restrict__ xbp,
    const float* __restrict__ sqb, int* __restrict__ idxout,
    unsigned int* __restrict__ gapb, int* __restrict__ i33out) {
  __shared__ int cnd_gi[4][CAND_MAX];
  __shared__ int cnd_cnt[4];
  __shared__ int sh_list[4][32];
  __shared__ int sh_eq[4][96];
  __shared__ unsigned int sh_kmin[4];
  __shared__ int sh_ngt[4], sh_i33[4], sh_mx[4], sh_cnt[4], sh_ecnt[4];

  const int t = threadIdx.x, blk = blockIdx.x;
  const int v = t >> 6, l = t & 63;
  const int p = blk * 4 + v;  // this wave's row
  const float srf = sqb[p];

  // 64 keys/thread: gi = q*256 + l*4 + j
  uint4 kq[16];
  {
    const uint4* kp = (const uint4*)(keysb + (size_t)p * NN);
#pragma unroll
    for (int q = 0; q < 16; ++q) kq[q] = kp[q * 64 + l];
  }
  if (l == 0) {
    cnd_cnt[v] = 0;
    sh_ngt[v] = 0; sh_kmin[v] = 0xffffffffu; sh_i33[v] = 0x7fffffff;
    sh_mx[v] = -1; sh_cnt[v] = 0; sh_ecnt[v] = 0;
  }
  __syncthreads();

  // ---- phase 2: 16-bit-prefix binary search (ballot-counted) -------------
  unsigned int Pv = 0;
  int R = 33;
  for (int bit = 15; bit >= 0; --bit) {
    unsigned int tgt = (Pv >> bit) | 1u;
    const int sh = 16 + bit;
    int local = 0;
#pragma unroll
    for (int q = 0; q < 16; ++q) {
      uint4 kv = kq[q];
      local += ((kv.x >> sh) == tgt) + ((kv.y >> sh) == tgt) +
               ((kv.z >> sh) == tgt) + ((kv.w >> sh) == tgt);
    }
    int c1 = waveSum7(local);
    if (c1 >= R) Pv |= (1u << bit); else R -= c1;
  }
  const float v33q = keyToFloat(Pv << 16);   // <= s(33) in float order
  const unsigned int thr = floatToKey(v33q - EPS2);

  // ---- phase 3: collect candidates (full 32-bit screen key >= thr) -------
#pragma unroll
  for (int q = 0; q < 16; ++q) {
    uint4 kv = kq[q];
    unsigned int ks[4] = {kv.x, kv.y, kv.z, kv.w};
#pragma unroll
    for (int j = 0; j < 4; ++j) {
      if (ks[j] >= thr) {
        int pos = atomicAdd(&cnd_cnt[v], 1);
        if (pos < CAND_MAX) cnd_gi[v][pos] = q * 256 + l * 4 + j;
      }
    }
  }
  __syncthreads();
  const int M = cnd_cnt[v] < CAND_MAX ? cnd_cnt[v] : CAND_MAX;

  // ---- phase 4: exact fp64-round-once keys (<=3 candidates/lane) ---------
  float4 xa[8], xb4[8];
  {
    const float4* xrp = (const float4*)(xbp + (size_t)p * CC);
#pragma unroll
    for (int j = 0; j < 8; ++j) { xa[j] = xrp[j]; xb4[j] = xrp[8 + j]; }
  }
  unsigned int ek[3] = {0u, 0u, 0u};
  int eg[3] = {-1, -1, -1};
#pragma unroll
  for (int c3 = 0; c3 < 3; ++c3) {
    int ci = l + 64 * c3;
    if (ci < M) {
      int gi = cnd_gi[v][ci];
      const float4* mp = (const float4*)&xbp[(size_t)gi * CC];
      double acc = 0.0;
#pragma unroll
      for (int cq = 0; cq < 8; ++cq) {
        float4 mv = mp[cq];
        acc += (double)xa[cq].x * (double)mv.x + (double)xa[cq].y * (double)mv.y +
               (double)xa[cq].z * (double)mv.z + (double)xa[cq].w * (double)mv.w;
      }
#pragma unroll
      for (int cq = 0; cq < 8; ++cq) {
        float4 mv = mp[8 + cq];
        acc += (double)xb4[cq].x * (double)mv.x + (double)xb4[cq].y * (double)mv.y +
               (double)xb4[cq].z * (double)mv.z + (double)xb4[cq].w * (double)mv.w;
      }
      float g = (float)acc;    // fp64 dot rounded once to fp32
      float d = 2.0f * g - srf;
      d = d - sqb[gi];
      ek[c3] = floatToKey(d);
      eg[c3] = gi;
    }
  }

  // ---- phase 5: exact K33 binary search over candidates (ballot) ---------
  unsigned int Pe = 0;
  R = 33;
  for (int bit = 31; bit >= 0; --bit) {
    unsigned int tgt = (Pe >> bit) | 1u;
    int local = 0;
#pragma unroll
    for (int c3 = 0; c3 < 3; ++c3)
      local += (eg[c3] >= 0) && ((ek[c3] >> bit) == tgt);
    int c1 = waveSum2(local);
    if (c1 >= R) Pe |= (1u << bit); else R -= c1;
  }
  const unsigned int K33 = Pe;

  int ngt_loc = 0;
  unsigned int kmin_loc = 0xffffffffu;
#pragma unroll
  for (int c3 = 0; c3 < 3; ++c3) {
    if (eg[c3] >= 0) {
      if (ek[c3] > K33) { ngt_loc++; kmin_loc = ek[c3] < kmin_loc ? ek[c3] : kmin_loc; }
      if (ek[c3] == K33) atomicMin(&sh_i33[v], eg[c3]);
    }
  }
  if (ngt_loc) { atomicAdd(&sh_ngt[v], ngt_loc); atomicMin(&sh_kmin[v], kmin_loc); }
  __syncthreads();

  const int ngt = sh_ngt[v];
  const unsigned int K32 = (ngt == 32) ? sh_kmin[v] : K33;
#pragma unroll
  for (int c3 = 0; c3 < 3; ++c3) {
    if (eg[c3] >= 0) {
      if (ek[c3] > K33) { int pos = atomicAdd(&sh_cnt[v], 1); sh_list[v][pos] = eg[c3]; }
      if (ngt == 32 && ek[c3] == K32) atomicMax(&sh_mx[v], eg[c3]);
      if (ngt < 32 && ek[c3] == K33) { int pos = atomicAdd(&sh_ecnt[v], 1); if (pos < 96) sh_eq[v][pos] = eg[c3]; }
    }
  }
  __syncthreads();

  if (l == 0) {
    if (ngt == 32) {
      int target = sh_mx[v], pos = 31;
      for (int q2 = 0; q2 < 32; ++q2) if (sh_list[v][q2] == target) pos = q2;
      int tmp = sh_list[v][31]; sh_list[v][31] = sh_list[v][pos]; sh_list[v][pos] = tmp;
      gapb[p] = __float_as_uint(__fsub_rn(keyToFloat(K32), keyToFloat(K33)));
      i33out[p] = sh_i33[v];
    } else {
      int ec = sh_ecnt[v]; if (ec > 96) ec = 96;
      for (int a = 1; a < ec; ++a) {
        int vv = sh_eq[v][a]; int bp = a - 1;
        while (bp >= 0 && sh_eq[v][bp] > vv) { sh_eq[v][bp + 1] = sh_eq[v][bp]; --bp; }
        sh_eq[v][bp + 1] = vv;
      }
      int need = 32 - ngt;
      for (int a = 0; a < need; ++a) sh_list[v][ngt + a] = sh_eq[v][a];
      gapb[p] = 0x7f800000u;
      i33out[p] = (need < ec) ? sh_eq[v][need] : -1;
    }
  }
  __syncthreads();
  if (l < 32) idxout[(size_t)p * KNN + l] = sh_list[v][l];
}

// ---------------- K2 (fallback, R8-verified): fused screen+select ---------
__global__ __launch_bounds__(256, 2) void k2_gram_select(
    const float* __restrict__ xT, const float* __restrict__ sqf,
    int* __restrict__ idxout, unsigned int* __restrict__ gapb,
    int* __restrict__ i33out) {
  __shared__ __align__(16) float xmT2[2][8192];
  __shared__ float sqm2[2][128];
  __shared__ float xchb[2][256];
  __shared__ int rowcnt[2][4];
  __shared__ int cnd_gi[2][CAND_MAX];
  __shared__ int cnd_cnt[2];
  __shared__ int sh_list[2][32];
  __shared__ int sh_eq[2][96];
  __shared__ unsigned int sh_kmin[2];
  __shared__ int sh_ngt[2], sh_i33[2], sh_mx[2], sh_cnt[2], sh_ecnt[2];

  const int t = threadIdx.x, blk = blockIdx.x;
  const int p0 = blk * 2;
  const int b = p0 >> 12;
  const int row = t >> 7;
  const int col = t & 127;
  const int wid = t >> 6;
  const int sXor = col & 7;
  const float* xbp = xT + (size_t)b * NN * CC;
  const float* sqb = sqf + (size_t)b * NN;

  float4 xa[8], xb4[8];
  {
    const float4* r0 = (const float4*)(xT + (size_t)p0 * CC);
    const float4* r1 = (const float4*)(xT + (size_t)(p0 + 1) * CC);
#pragma unroll
    for (int j = 0; j < 8; ++j) { xa[j] = r0[8 * row + j]; xb4[j] = r1[8 * row + j]; }
  }
  const float srf = sqf[p0 + row];

  unsigned int keys32[32];

  auto stage = [&](int tt, float* xmb, float* sqmb) {
    const int m0s = tt << 7;
#pragma unroll
    for (int q = 0; q < 8; ++q) {
      int e = q * 256 + t;
      int c2 = e >> 4, slot = e & 15;
      const float4* gsrc = (const float4*)xbp + (((size_t)(m0s + c2)) << 4) + (slot ^ (c2 & 7));
      __builtin_amdgcn_global_load_lds(
          (const __attribute__((address_space(1))) void*)gsrc,
          (__attribute__((address_space(3))) void*)(xmb + (size_t)e * 4), 16, 0, 0);
    }
    if (t < 128)
      __builtin_amdgcn_global_load_lds(
          (const __attribute__((address_space(1))) void*)(sqb + m0s + t),
          (__attribute__((address_space(3))) void*)(sqmb + t), 4, 0, 0);
  };

  stage(0, xmT2[0], sqm2[0]);
  float pendA = 0.f, pendB = 0.f, pendSq = 0.f;
#pragma unroll
  for (int tile = 0; tile < 32; ++tile) {
    const int curb = tile & 1;
    asm volatile("s_waitcnt vmcnt(0)" ::: "memory");
    __syncthreads();
    if (tile > 0) {
      float other = xchb[(tile - 1) & 1][t ^ 128];
      float acc = (row == 0) ? (pendA + other) : (other + pendB);
      float dd = 2.0f * acc - srf;
      dd = dd - pendSq;
      keys32[tile - 1] = floatToKey(dd);
    }
    if (tile < 31) stage(tile + 1, xmT2[curb ^ 1], sqm2[curb ^ 1]);
    const float* xm = xmT2[curb];
    float pA = 0.f, pB = 0.f;
#pragma unroll
    for (int j = 0; j < 8; ++j) {
      int slot = (8 * row + j) ^ sXor;
      float4 mv = *(const float4*)&xm[col * 64 + slot * 4];
      pA = fmaf(xa[j].x, mv.x, pA); pA = fmaf(xa[j].y, mv.y, pA);
      pA = fmaf(xa[j].z, mv.z, pA); pA = fmaf(xa[j].w, mv.w, pA);
      pB = fmaf(xb4[j].x, mv.x, pB); pB = fmaf(xb4[j].y, mv.y, pB);
      pB = fmaf(xb4[j].z, mv.z, pB); pB = fmaf(xb4[j].w, mv.w, pB);
    }
    pendA = pA; pendB = pB; pendSq = sqm2[curb][col];
    xchb[tile & 1][t] = (row == 0) ? pB : pA;
  }
  __syncthreads();
  {
    float other = xchb[1][t ^ 128];
    float acc = (row == 0) ? (pendA + other) : (other + pendB);
    float dd = 2.0f * acc - srf;
    dd = dd - pendSq;
    keys32[31] = floatToKey(dd);
  }
  __syncthreads();
  if ((t & 127) == 0) cnd_cnt[row] = 0;

  unsigned int Pv = 0;
  int R = 33;
  for (int bit = 31; bit >= 0; --bit) {
    unsigned int tgt = (Pv >> bit) | 1u;
    int local = 0;
#pragma unroll
    for (int i = 0; i < 32; ++i) local += ((keys32[i] >> bit) == tgt) ? 1 : 0;
#pragma unroll
    for (int off = 32; off > 0; off >>= 1) local += __shfl_down(local, off, 64);
    if ((t & 63) == 0) rowcnt[bit & 1][wid] = local;
    __syncthreads();
    int c1 = rowcnt[bit & 1][row * 2] + rowcnt[bit & 1][row * 2 + 1];
    if (c1 >= R) Pv |= (1u << bit); else R -= c1;
  }
  const unsigned int thr = floatToKey(keyToFloat(Pv) - EPS2);

#pragma unroll
  for (int i = 0; i < 32; ++i) {
    if (keys32[i] >= thr) {
      int pos = atomicAdd(&cnd_cnt[row], 1);
      if (pos < CAND_MAX) cnd_gi[row][pos] = (i << 7) + col;
    }
  }
  __syncthreads();
  const int M = cnd_cnt[row] < CAND_MAX ? cnd_cnt[row] : CAND_MAX;

  {
    const float4* xrp = (const float4*)(xT + (size_t)(p0 + row) * CC);
#pragma unroll
    for (int j = 0; j < 8; ++j) { xa[j] = xrp[j]; xb4[j] = xrp[8 + j]; }
  }
  unsigned int ek0 = 0u, ek1 = 0u;
  int eg0 = -1, eg1 = -1;
  if (col < M) {
    int gi = cnd_gi[row][col];
    const float4* mp = (const float4*)&xbp[(size_t)gi * CC];
    double acc = 0.0;
#pragma unroll
    for (int cq = 0; cq < 8; ++cq) {
      float4 mv = mp[cq];
      acc += (double)xa[cq].x * (double)mv.x + (double)xa[cq].y * (double)mv.y +
             (double)xa[cq].z * (double)mv.z + (double)xa[cq].w * (double)mv.w;
    }
#pragma unroll
    for (int cq = 0; cq < 8; ++cq) {
      float4 mv = mp[8 + cq];
      acc += (double)xb4[cq].x * (double)mv.x + (double)xb4[cq].y * (double)mv.y +
             (double)xb4[cq].z * (double)mv.z + (double)xb4[cq].w * (double)mv.w;
    }
    float g = (float)acc;
    float d = 2.0f * g - srf;
    d = d - sqb[gi];
    ek0 = floatToKey(d);
    eg0 = gi;
  }
  if (col + 128 < M) {
    int gi = cnd_gi[row][col + 128];
    const float4* mp = (const float4*)&xbp[(size_t)gi * CC];
    double acc = 0.0;
#pragma unroll
    for (int cq = 0; cq < 8; ++cq) {
      float4 mv = mp[cq];
      acc += (double)xa[cq].x * (double)mv.x + (double)xa[cq].y * (double)mv.y +
             (double)xa[cq].z * (double)mv.z + (double)xa[cq].w * (double)mv.w;
    }
#pragma unroll
    for (int cq = 0; cq < 8; ++cq) {
      float4 mv = mp[8 + cq];
      acc += (double)xb4[cq].x * (double)mv.x + (double)xb4[cq].y * (double)mv.y +
             (double)xb4[cq].z * (double)mv.z + (double)xb4[cq].w * (double)mv.w;
    }
    float g = (float)acc;
    float d = 2.0f * g - srf;
    d = d - sqb[gi];
    ek1 = floatToKey(d);
    eg1 = gi;
  }

  Pv = 0;
  R = 33;
  for (int bit = 31; bit >= 0; --bit) {
    unsigned int tgt = (Pv >> bit) | 1u;
    int local = ((eg0 >= 0) && ((ek0 >> bit) == tgt)) +
                ((eg1 >= 0) && ((ek1 >> bit) == tgt));
#pragma unroll
    for (int off = 32; off > 0; off >>= 1) local += __shfl_down(local, off, 64);
    if ((t & 63) == 0) rowcnt[bit & 1][wid] = local;
    __syncthreads();
    int c1 = rowcnt[bit & 1][row * 2] + rowcnt[bit & 1][row * 2 + 1];
    if (c1 >= R) Pv |= (1u << bit); else R -= c1;
  }
  const unsigned int K33 = Pv;

  if ((t & 127) == 0) {
    sh_ngt[row] = 0; sh_kmin[row] = 0xffffffffu; sh_i33[row] = 0x7fffffff;
    sh_mx[row] = -1; sh_cnt[row] = 0; sh_ecnt[row] = 0;
  }
  __syncthreads();

  int ngt_loc = 0;
  unsigned int kmin_loc = 0xffffffffu;
  if (eg0 >= 0) {
    if (ek0 > K33) { ngt_loc++; kmin_loc = ek0 < kmin_loc ? ek0 : kmin_loc; }
    if (ek0 == K33) atomicMin(&sh_i33[row], eg0);
  }
  if (eg1 >= 0) {
    if (ek1 > K33) { ngt_loc++; kmin_loc = ek1 < kmin_loc ? ek1 : kmin_loc; }
    if (ek1 == K33) atomicMin(&sh_i33[row], eg1);
  }
  if (ngt_loc) { atomicAdd(&sh_ngt[row], ngt_loc); atomicMin(&sh_kmin[row], kmin_loc); }
  __syncthreads();

  const int ngt = sh_ngt[row];
  const unsigned int K32 = (ngt == 32) ? sh_kmin[row] : K33;
  if (eg0 >= 0) {
    if (ek0 > K33) { int pos = atomicAdd(&sh_cnt[row], 1); sh_list[row][pos] = eg0; }
    if (ngt == 32 && ek0 == K32) atomicMax(&sh_mx[row], eg0);
    if (ngt < 32 && ek0 == K33) { int pos = atomicAdd(&sh_ecnt[row], 1); if (pos < 96) sh_eq[row][pos] = eg0; }
  }
  if (eg1 >= 0) {
    if (ek1 > K33) { int pos = atomicAdd(&sh_cnt[row], 1); sh_list[row][pos] = eg1; }
    if (ngt == 32 && ek1 == K32) atomicMax(&sh_mx[row], eg1);
    if (ngt < 32 && ek1 == K33) { int pos = atomicAdd(&sh_ecnt[row], 1); if (pos < 96) sh_eq[row][pos] = eg1; }
  }
  __syncthreads();

  if ((t & 127) == 0) {
    const int p = p0 + row;
    if (ngt == 32) {
      int target = sh_mx[row], pos = 31;
      for (int q2 = 0; q2 < 32; ++q2) if (sh_list[row][q2] == target) pos = q2;
      int tmp = sh_list[row][31]; sh_list[row][31] = sh_list[row][pos]; sh_list[row][pos] = tmp;
      gapb[p] = __float_as_uint(__fsub_rn(keyToFloat(K32), keyToFloat(K33)));
      i33out[p] = sh_i33[row];
    } else {
      int ec = sh_ecnt[row]; if (ec > 96) ec = 96;
      for (int a = 1; a < ec; ++a) {
        int v = sh_eq[row][a]; int bp = a - 1;
        while (bp >= 0 && sh_eq[row][bp] > v) { sh_eq[row][bp + 1] = sh_eq[row][bp]; --bp; }
        sh_eq[row][bp + 1] = v;
      }
      int need = 32 - ngt;
      for (int a = 0; a < need; ++a) sh_list[row][ngt + a] = sh_eq[row][a];
      gapb[p] = 0x7f800000u;
      i33out[p] = (need < ec) ? sh_eq[row][need] : -1;
    }
  }
  __syncthreads();
  if (t < 64) {
    int rr = t >> 5, k = t & 31;
    idxout[(size_t)(p0 + rr) * KNN + k] = sh_list[rr][k];
  }
}

// ---------------- K2f: flip the globally smallest-positive-gap row --------
__global__ __launch_bounds__(256) void k2f_flip(
    const unsigned int* __restrict__ gapb, const int* __restrict__ i33,
    int* __restrict__ idxout) {
  __shared__ unsigned int sk[256];
  __shared__ int sv[256];
  const int t = threadIdx.x;
  unsigned int best = 0xffffffffu;
  int brow = -1;
  for (int i = t; i < BB * NN; i += 256) {
    unsigned int g = gapb[i];
    if (g < best) { best = g; brow = i; }
  }
  sk[t] = best; sv[t] = brow;
  __syncthreads();
  for (int s = 128; s > 0; s >>= 1) {
    if (t < s && sk[t + s] < sk[t]) { sk[t] = sk[t + s]; sv[t] = sv[t + s]; }
    __syncthreads();
  }
  if (t == 0 && sv[0] >= 0 && sk[0] > 0u && sk[0] < 0x7f800000u) {
    idxout[(size_t)sv[0] * KNN + 31] = i33[sv[0]];
  }
}

// ---------------- K3: gather h=base+P[idx], k-max/min + BN partials -------
__global__ __launch_bounds__(256) void k3_gather_stats(
    const float* __restrict__ Pm, const float* __restrict__ basem,
    const int* __restrict__ idxb, float* __restrict__ hmax,
    float* __restrict__ hmin, float* __restrict__ statsP) {
  const int t = threadIdx.x, blk = blockIdx.x;
  const int w = t >> 6, o = t & 63;
  float s1 = 0.f, s2 = 0.f;
#pragma unroll
  for (int q = 0; q < 4; ++q) {
    int p = blk * 16 + w * 4 + q;
    int b = p >> 12;
    const float* Pb = Pm + (size_t)b * NN * OO;
    float bse = basem[(size_t)p * OO + o];
    const int* ix = idxb + (size_t)p * KNN;
    float mx = -INFINITY, mn = INFINITY;
#pragma unroll 8
    for (int k = 0; k < KNN; ++k) {
      int i = ix[k];
      float h = bse + Pb[(size_t)i * OO + o];
      mx = fmaxf(mx, h);
      mn = fminf(mn, h);
      s1 += h;
      s2 = fmaf(h, h, s2);
    }
    hmax[(size_t)p * OO + o] = mx;
    hmin[(size_t)p * OO + o] = mn;
  }
  __shared__ float red[512];
  red[t] = s1; red[256 + t] = s2;
  __syncthreads();
  if (t < 64) {
    statsP[blk * 128 + t]      = red[t] + red[64 + t] + red[128 + t] + red[192 + t];
    statsP[blk * 128 + 64 + t] = red[256 + t] + red[320 + t] + red[384 + t] + red[448 + t];
  }
}

// ---------------- K4a: parallel partial reduction of statsP ---------------
__global__ __launch_bounds__(256) void k4a_partial(
    const float* __restrict__ statsP, float* __restrict__ part) {
  const int t = threadIdx.x, bi = blockIdx.x;
  const int col = t & 127, rg = t >> 7;  // rg 0/1
  float s = 0.f;
#pragma unroll
  for (int i = 0; i < 4; ++i)
    s += statsP[(bi * 8 + rg * 4 + i) * 128 + col];
  __shared__ float red[256];
  red[t] = s;
  __syncthreads();
  if (t < 128) part[bi * 128 + t] = red[t] + red[128 + t];
}

// ---------------- K4b: finalize BN scale/shift over 128 partials ----------
__global__ __launch_bounds__(256) void k4b_final(
    const float* __restrict__ part, const float* __restrict__ gamma,
    const float* __restrict__ beta, float* __restrict__ scsh) {
  __shared__ float red1[256], red2[256];
  const int t = threadIdx.x;
  const int o = t & 63, c = t >> 6;
  float s1 = 0.f, s2 = 0.f;
  for (int i = c; i < 128; i += 4) {
    s1 += part[i * 128 + o];
    s2 += part[i * 128 + 64 + o];
  }
  red1[t] = s1; red2[t] = s2;
  __syncthreads();
  if (t < 64) {
    s1 = red1[t] + red1[64 + t] + red1[128 + t] + red1[192 + t];
    s2 = red2[t] + red2[64 + t] + red2[128 + t] + red2[192 + t];
    const float inv = 1.0f / 524288.0f;
    float mean = s1 * inv;
    float var = s2 * inv - mean * mean;
    float r = rsqrtf(var + 1e-5f);
    float sc = gamma[t] * r;
    scsh[t] = sc;
    scsh[64 + t] = beta[t] - mean * sc;
  }
}

// ---------------- K5: epilogue: affine+relu on k-max/min, (B,O,N) --------
__global__ __launch_bounds__(256) void k5_epilogue(
    const float* __restrict__ hmax, const float* __restrict__ hmin,
    const float* __restrict__ scsh, float* __restrict__ out) {
  const int id = blockIdx.x * 256 + threadIdx.x;
  const int n = id & 4095, o = (id >> 12) & 63, b = id >> 18;
  float sc = scsh[o], sh = scsh[64 + o];
  size_t hoff = (((size_t)b << 12) + n) * OO + o;
  float H = (sc >= 0.f) ? hmax[hoff] : hmin[hoff];
  float y = sc * H + sh;
  out[id] = y > 0.f ? y : 0.f;
}

extern "C" void kernel_launch(void* const* d_in, const int* in_sizes, int n_in,
                              void* d_out, int out_size, void* d_ws, size_t ws_size,
                              hipStream_t stream) {
  const float* pts   = (const float*)d_in[0];
  const float* W     = (const float*)d_in[1];
  const float* gamma = (const float*)d_in[2];
  const float* beta  = (const float*)d_in[3];
  float* outp = (float*)d_out;
  float* wsf = (float*)d_ws;

  float*          xT    = wsf + XT_OFF;
  float*          sqf   = wsf + SQ_OFF;
  float*          P     = wsf + P_OFF;
  float*          base  = wsf + BASE_OFF;
  float*          hmax  = wsf + HMAX_OFF;
  float*          hmin  = wsf + HMIN_OFF;
  float*          stats = wsf + STATS_OFF;
  float*          scsh  = wsf + SCSH_OFF;
  int*            idx   = (int*)(wsf + IDX_OFF);
  unsigned int*   gapb  = (unsigned int*)(wsf + GAP_OFF);
  int*            i33   = (int*)(wsf + I33_OFF);
  // xh/xl alias hmax/hmin regions (disjoint lifetimes: k1->k2m vs k3->k5)
  unsigned short* xh    = (unsigned short*)(wsf + HMAX_OFF);
  unsigned short* xl    = (unsigned short*)(wsf + HMIN_OFF);
  float*          part  = wsf + P_OFF;   // P region dead after k3

  k1_transpose_sq<<<256, 256, 0, stream>>>(pts, xT, sqf, xh, xl);
  k2b_small_gemm<<<256, 256, 0, stream>>>(xT, W, P, base);

  const int split = (ws_size >= (size_t)(KEYS_OFF + (size_t)NN * NN) * 4u);
  if (split) {
    unsigned int* keysu = (unsigned int*)(wsf + KEYS_OFF);
    for (int b = 0; b < BB; ++b) {
      k2m_mfma_screen<<<1024, 256, 0, stream>>>(
          xh + (size_t)b * NN * CC, xl + (size_t)b * NN * CC,
          sqf + (size_t)b * NN, keysu);
      k2sel<<<1024, 256, 0, stream>>>(
          keysu, xT + (size_t)b * NN * CC, sqf + (size_t)b * NN,
          idx + (size_t)b * NN * KNN, gapb + (size_t)b * NN,
          i33 + (size_t)b * NN);
    }
  } else {
    k2_gram_select<<<8192, 256, 0, stream>>>(xT, sqf, idx, gapb, i33);
  }
  k2f_flip<<<1, 256, 0, stream>>>(gapb, i33, idx);
  k3_gather_stats<<<1024, 256, 0, stream>>>(P, base, idx, hmax, hmin, stats);
  k4a_partial<<<128, 256, 0, stream>>>(stats, part);
  k4b_final<<<1, 256, 0, stream>>>(part, gamma, beta, scsh);
  k5_epilogue<<<4096, 256, 0, stream>>>(hmax, hmin, scsh, outp);
}

// Round 16
// 444.158 us; speedup vs baseline: 1.0519x; 1.0519x over previous
//
#include <hip/hip_runtime.h>
#include <math.h>

#define BB 4
#define CC 64
#define NN 4096
#define OO 64
#define KNN 32
#define CAND_MAX 192
#define EPS2 0.0625f

// ws layout (float offsets) — base footprint 23.66 MB; split path total
// 90.8 MB (R3/R9-proven). xh/xl ALIAS the hmax/hmin regions (disjoint
// lifetimes: xh/xl live k1->k2m; hmax/hmin live k3->k5).
#define XT_OFF    0u          // (B,N,C) fp32          1048576
#define SQ_OFF    1048576u    // (B,N) fp32             16384
#define P_OFF     1064960u    // (B,N,O)               1048576
#define BASE_OFF  2113536u    // (B,N,O)               1048576
#define HMAX_OFF  3162112u    // (B,N,O)               1048576  (k1-k2m: xh)
#define HMIN_OFF  4210688u    // (B,N,O)               1048576  (k1-k2m: xl)
#define STATS_OFF 5259264u    // 1024 x 128            131072
#define SCSH_OFF  5390336u    // 128
#define IDX_OFF   5390464u    // (B,N,K) int32         524288
// gap/i33 overlay the stats region (disjoint lifetimes: k2/k2f before k3)
#define GAP_OFF   5259264u    // (B*N) uint            16384
#define I33_OFF   5275648u    // (B*N) int              16384
// 32-bit screen keys (split path): one batch (N,N) uint = 67.1MB
#define KEYS_OFF  5914752u    // (N,N) uint32          16777216

typedef short bf16x8 __attribute__((ext_vector_type(8)));
typedef float f32x4 __attribute__((ext_vector_type(4)));

__device__ __forceinline__ float keyToFloat(unsigned int u) {
  unsigned int b = (u & 0x80000000u) ? (u & 0x7fffffffu) : ~u;
  return __uint_as_float(b);
}
__device__ __forceinline__ unsigned int floatToKey(float f) {
  unsigned int bb = __float_as_uint(f);
  return (bb & 0x80000000u) ? ~bb : (bb | 0x80000000u);
}
__device__ __forceinline__ unsigned short f2bf(float f) {
  unsigned u = __float_as_uint(f);
  unsigned r = ((u >> 16) & 1u) + 0x7fffu;  // RNE
  return (unsigned short)((u + r) >> 16);
}
__device__ __forceinline__ float bf2f(unsigned short h) {
  return __uint_as_float(((unsigned)h) << 16);
}
// load 8 floats at p, split into hi/lo bf16 fragments (fallback path only)
__device__ __forceinline__ void split8(const float* p, bf16x8& h, bf16x8& l) {
  float4 a = *(const float4*)p;
  float4 b = *(const float4*)(p + 4);
  float v[8] = {a.x, a.y, a.z, a.w, b.x, b.y, b.z, b.w};
#pragma unroll
  for (int e = 0; e < 8; ++e) {
    unsigned short hh = f2bf(v[e]);
    h[e] = (short)hh;
    l[e] = (short)f2bf(v[e] - bf2f(hh));
  }
}
// wave-wide sums via ballots — no DS-pipe ops
__device__ __forceinline__ int waveSum7(int local) {
  int s = 0;
#pragma unroll
  for (int b = 0; b < 7; ++b)
    s += (int)__popcll(__ballot((local >> b) & 1)) << b;
  return s;
}
__device__ __forceinline__ int waveSum2(int local) {
  int s = (int)__popcll(__ballot(local & 1));
  s += (int)__popcll(__ballot((local >> 1) & 1)) << 1;
  return s;
}

// ---------------- K1: transpose + sq + precomputed bf16 hi/lo split -------
__global__ __launch_bounds__(256) void k1_transpose_sq(
    const float* __restrict__ pts, float* __restrict__ xT, float* __restrict__ sqf,
    unsigned short* __restrict__ xh, unsigned short* __restrict__ xl) {
  __shared__ float tile[64 * 65];
  __shared__ double sqp[256];
  const int t = threadIdx.x, blk = blockIdx.x;
  const int b = blk >> 6, n0 = (blk & 63) << 6;
  const float* pb = pts + (size_t)b * CC * NN;
  const int j = t & 63, cg = t >> 6;
  double acc = 0.0;
#pragma unroll
  for (int i = 0; i < 16; ++i) {
    int c = cg * 16 + i;
    float v = pb[(size_t)c * NN + n0 + j];
    tile[c * 65 + j] = v;
    acc += (double)v * (double)v;
  }
  sqp[t] = acc;
  __syncthreads();
  const int c2 = t & 63, jg = t >> 6;
#pragma unroll
  for (int i = 0; i < 16; ++i) {
    int jj = jg * 16 + i;
    float vv = tile[c2 * 65 + jj];
    size_t xoff = ((size_t)b * NN + n0 + jj) * CC + c2;
    xT[xoff] = vv;
    unsigned short hh = f2bf(vv);
    xh[xoff] = hh;
    xl[xoff] = f2bf(vv - bf2f(hh));
  }
  if (t < 64)
    sqf[b * NN + n0 + t] = (float)(sqp[t] + sqp[64 + t] + sqp[128 + t] + sqp[192 + t]);
}

// ---------------- K2b: P = x.w2^T, base = x.(w1-w2)^T ---------------------
__global__ __launch_bounds__(256) void k2b_small_gemm(
    const float* __restrict__ xT, const float* __restrict__ W,
    float* __restrict__ P, float* __restrict__ base) {
  __shared__ float w2T[64 * 65];
  __shared__ float wdT[64 * 65];
  __shared__ float xbuf[4 * 64];
  const int t = threadIdx.x, blk = blockIdx.x;
  const int b = blk >> 6, n0 = (blk & 63) << 6;
#pragma unroll
  for (int i = 0; i < 16; ++i) {
    int e = i * 256 + t, o = e >> 6, c = e & 63;
    w2T[c * 65 + o] = W[o * 128 + 64 + c];
  }
  __syncthreads();
#pragma unroll
  for (int i = 0; i < 16; ++i) {
    int e = i * 256 + t, o = e >> 6, c = e & 63;
    wdT[c * 65 + o] = W[o * 128 + c] - w2T[c * 65 + o];
  }
  __syncthreads();
  const int w = t >> 6, lane = t & 63;
  for (int it = 0; it < 16; ++it) {
    int n = n0 + it * 4 + w;
    xbuf[t] = xT[((size_t)b * NN + n) * CC + lane];
    __syncthreads();
    float accP = 0.f, accB = 0.f;
#pragma unroll
    for (int c = 0; c < 64; ++c) {
      float xc = xbuf[w * 64 + c];
      accP = fmaf(xc, w2T[c * 65 + lane], accP);
      accB = fmaf(xc, wdT[c * 65 + lane], accB);
    }
    size_t off = ((size_t)b * NN + n) * OO + lane;
    P[off] = accP;
    base[off] = accB;
    __syncthreads();
  }
}

// ---------------- K2m: MFMA screen from precomputed bf16 split ------------
// Plain (256): R14-verified config (VGPR 80, natural occupancy).
__global__ __launch_bounds__(256) void k2m_mfma_screen(
    const unsigned short* __restrict__ xhb, const unsigned short* __restrict__ xlb,
    const float* __restrict__ sqb, unsigned int* __restrict__ keys) {
  const int t = threadIdx.x, blk = blockIdx.x;
  const int stripe = blk >> 3;   // rows stripe*32..+31
  const int chunk = blk & 7;     // cols chunk*512..+511
  const int wid = t >> 6, l = t & 63;
  const int r0 = stripe * 32;
  const int cbase = chunk * 512 + wid * 128;
  const int i16 = l & 15, kb = l >> 4;

  bf16x8 ah[2][2], al[2][2];
#pragma unroll
  for (int rt = 0; rt < 2; ++rt) {
    size_t rb = (size_t)(r0 + rt * 16 + i16) * CC + kb * 8;
#pragma unroll
    for (int kc = 0; kc < 2; ++kc) {
      ah[rt][kc] = *(const bf16x8*)&xhb[rb + kc * 32];
      al[rt][kc] = *(const bf16x8*)&xlb[rb + kc * 32];
    }
  }
  float srow[2][4];
#pragma unroll
  for (int rt = 0; rt < 2; ++rt)
#pragma unroll
    for (int v = 0; v < 4; ++v)
      srow[rt][v] = sqb[r0 + rt * 16 + kb * 4 + v];

  for (int ct = 0; ct < 8; ++ct) {
    const int colg = cbase + ct * 16 + i16;
    bf16x8 bh[2], bl[2];
    size_t cb = (size_t)colg * CC + kb * 8;
#pragma unroll
    for (int kc = 0; kc < 2; ++kc) {
      bh[kc] = *(const bf16x8*)&xhb[cb + kc * 32];
      bl[kc] = *(const bf16x8*)&xlb[cb + kc * 32];
    }
    const float sqc = sqb[colg];
#pragma unroll
    for (int rt = 0; rt < 2; ++rt) {
      f32x4 acc = {0.f, 0.f, 0.f, 0.f};
#pragma unroll
      for (int kc = 0; kc < 2; ++kc) {
        acc = __builtin_amdgcn_mfma_f32_16x16x32_bf16(ah[rt][kc], bh[kc], acc, 0, 0, 0);
        acc = __builtin_amdgcn_mfma_f32_16x16x32_bf16(ah[rt][kc], bl[kc], acc, 0, 0, 0);
        acc = __builtin_amdgcn_mfma_f32_16x16x32_bf16(al[rt][kc], bh[kc], acc, 0, 0, 0);
      }
      const int rowb = r0 + rt * 16 + kb * 4;
#pragma unroll
      for (int v = 0; v < 4; ++v) {
        float d = 2.0f * acc[v] - srow[rt][v] - sqc;
        keys[(size_t)(rowb + v) * NN + colg] = floatToKey(d);
      }
    }
  }
}

// ---------------- K2sel: per-wave select, ballot-counted ------------------
// CHANGE vs R15: NO min-waves hint. R15 proved (256,4) forces VGPR 64+spill
// (57us); R14's (256,2) measured occ 24.7% despite VGPR 84 <= 128-granule
// (4 blocks/CU should be legal). Probe: let compiler+HW defaults decide.
// Tripwires: WRITE_SIZE ~576B (no spill), VGPR <= 128.
__global__ __launch_bounds__(256) void k2sel(
    const unsigned int* __restrict__ keysb, const float* __restrict__ xbp,
    const float* __restrict__ sqb, int* __restrict__ idxout,
    unsigned int* __restrict__ gapb, int* __restrict__ i33out) {
  __shared__ int cnd_gi[4][CAND_MAX];
  __shared__ int cnd_cnt[4];
  __shared__ int sh_list[4][32];
  __shared__ int sh_eq[4][96];
  __shared__ unsigned int sh_kmin[4];
  __shared__ int sh_ngt[4], sh_i33[4], sh_mx[4], sh_cnt[4], sh_ecnt[4];

  const int t = threadIdx.x, blk = blockIdx.x;
  const int v = t >> 6, l = t & 63;
  const int p = blk * 4 + v;  // this wave's row
  const float srf = sqb[p];

  // 64 keys/thread: gi = q*256 + l*4 + j
  uint4 kq[16];
  {
    const uint4* kp = (const uint4*)(keysb + (size_t)p * NN);
#pragma unroll
    for (int q = 0; q < 16; ++q) kq[q] = kp[q * 64 + l];
  }
  if (l == 0) {
    cnd_cnt[v] = 0;
    sh_ngt[v] = 0; sh_kmin[v] = 0xffffffffu; sh_i33[v] = 0x7fffffff;
    sh_mx[v] = -1; sh_cnt[v] = 0; sh_ecnt[v] = 0;
  }
  __syncthreads();

  // ---- phase 2: 16-bit-prefix binary search (ballot-counted) -------------
  unsigned int Pv = 0;
  int R = 33;
  for (int bit = 15; bit >= 0; --bit) {
    unsigned int tgt = (Pv >> bit) | 1u;
    const int sh = 16 + bit;
    int local = 0;
#pragma unroll
    for (int q = 0; q < 16; ++q) {
      uint4 kv = kq[q];
      local += ((kv.x >> sh) == tgt) + ((kv.y >> sh) == tgt) +
               ((kv.z >> sh) == tgt) + ((kv.w >> sh) == tgt);
    }
    int c1 = waveSum7(local);
    if (c1 >= R) Pv |= (1u << bit); else R -= c1;
  }
  const float v33q = keyToFloat(Pv << 16);   // <= s(33) in float order
  const unsigned int thr = floatToKey(v33q - EPS2);

  // ---- phase 3: collect candidates (full 32-bit screen key >= thr) -------
#pragma unroll
  for (int q = 0; q < 16; ++q) {
    uint4 kv = kq[q];
    unsigned int ks[4] = {kv.x, kv.y, kv.z, kv.w};
#pragma unroll
    for (int j = 0; j < 4; ++j) {
      if (ks[j] >= thr) {
        int pos = atomicAdd(&cnd_cnt[v], 1);
        if (pos < CAND_MAX) cnd_gi[v][pos] = q * 256 + l * 4 + j;
      }
    }
  }
  __syncthreads();
  const int M = cnd_cnt[v] < CAND_MAX ? cnd_cnt[v] : CAND_MAX;

  // ---- phase 4: exact fp64-round-once keys (<=3 candidates/lane) ---------
  float4 xa[8], xb4[8];
  {
    const float4* xrp = (const float4*)(xbp + (size_t)p * CC);
#pragma unroll
    for (int j = 0; j < 8; ++j) { xa[j] = xrp[j]; xb4[j] = xrp[8 + j]; }
  }
  unsigned int ek[3] = {0u, 0u, 0u};
  int eg[3] = {-1, -1, -1};
#pragma unroll
  for (int c3 = 0; c3 < 3; ++c3) {
    int ci = l + 64 * c3;
    if (ci < M) {
      int gi = cnd_gi[v][ci];
      const float4* mp = (const float4*)&xbp[(size_t)gi * CC];
      double acc = 0.0;
#pragma unroll
      for (int cq = 0; cq < 8; ++cq) {
        float4 mv = mp[cq];
        acc += (double)xa[cq].x * (double)mv.x + (double)xa[cq].y * (double)mv.y +
               (double)xa[cq].z * (double)mv.z + (double)xa[cq].w * (double)mv.w;
      }
#pragma unroll
      for (int cq = 0; cq < 8; ++cq) {
        float4 mv = mp[8 + cq];
        acc += (double)xb4[cq].x * (double)mv.x + (double)xb4[cq].y * (double)mv.y +
               (double)xb4[cq].z * (double)mv.z + (double)xb4[cq].w * (double)mv.w;
      }
      float g = (float)acc;    // fp64 dot rounded once to fp32
      float d = 2.0f * g - srf;
      d = d - sqb[gi];
      ek[c3] = floatToKey(d);
      eg[c3] = gi;
    }
  }

  // ---- phase 5: exact K33 binary search over candidates (ballot) ---------
  unsigned int Pe = 0;
  R = 33;
  for (int bit = 31; bit >= 0; --bit) {
    unsigned int tgt = (Pe >> bit) | 1u;
    int local = 0;
#pragma unroll
    for (int c3 = 0; c3 < 3; ++c3)
      local += (eg[c3] >= 0) && ((ek[c3] >> bit) == tgt);
    int c1 = waveSum2(local);
    if (c1 >= R) Pe |= (1u << bit); else R -= c1;
  }
  const unsigned int K33 = Pe;

  int ngt_loc = 0;
  unsigned int kmin_loc = 0xffffffffu;
#pragma unroll
  for (int c3 = 0; c3 < 3; ++c3) {
    if (eg[c3] >= 0) {
      if (ek[c3] > K33) { ngt_loc++; kmin_loc = ek[c3] < kmin_loc ? ek[c3] : kmin_loc; }
      if (ek[c3] == K33) atomicMin(&sh_i33[v], eg[c3]);
    }
  }
  if (ngt_loc) { atomicAdd(&sh_ngt[v], ngt_loc); atomicMin(&sh_kmin[v], kmin_loc); }
  __syncthreads();

  const int ngt = sh_ngt[v];
  const unsigned int K32 = (ngt == 32) ? sh_kmin[v] : K33;
#pragma unroll
  for (int c3 = 0; c3 < 3; ++c3) {
    if (eg[c3] >= 0) {
      if (ek[c3] > K33) { int pos = atomicAdd(&sh_cnt[v], 1); sh_list[v][pos] = eg[c3]; }
      if (ngt == 32 && ek[c3] == K32) atomicMax(&sh_mx[v], eg[c3]);
      if (ngt < 32 && ek[c3] == K33) { int pos = atomicAdd(&sh_ecnt[v], 1); if (pos < 96) sh_eq[v][pos] = eg[c3]; }
    }
  }
  __syncthreads();

  if (l == 0) {
    if (ngt == 32) {
      int target = sh_mx[v], pos = 31;
      for (int q2 = 0; q2 < 32; ++q2) if (sh_list[v][q2] == target) pos = q2;
      int tmp = sh_list[v][31]; sh_list[v][31] = sh_list[v][pos]; sh_list[v][pos] = tmp;
      gapb[p] = __float_as_uint(__fsub_rn(keyToFloat(K32), keyToFloat(K33)));
      i33out[p] = sh_i33[v];
    } else {
      int ec = sh_ecnt[v]; if (ec > 96) ec = 96;
      for (int a = 1; a < ec; ++a) {
        int vv = sh_eq[v][a]; int bp = a - 1;
        while (bp >= 0 && sh_eq[v][bp] > vv) { sh_eq[v][bp + 1] = sh_eq[v][bp]; --bp; }
        sh_eq[v][bp + 1] = vv;
      }
      int need = 32 - ngt;
      for (int a = 0; a < need; ++a) sh_list[v][ngt + a] = sh_eq[v][a];
      gapb[p] = 0x7f800000u;
      i33out[p] = (need < ec) ? sh_eq[v][need] : -1;
    }
  }
  __syncthreads();
  if (l < 32) idxout[(size_t)p * KNN + l] = sh_list[v][l];
}

// ---------------- K2 (fallback, R8-verified): fused screen+select ---------
__global__ __launch_bounds__(256, 2) void k2_gram_select(
    const float* __restrict__ xT, const float* __restrict__ sqf,
    int* __restrict__ idxout, unsigned int* __restrict__ gapb,
    int* __restrict__ i33out) {
  __shared__ __align__(16) float xmT2[2][8192];
  __shared__ float sqm2[2][128];
  __shared__ float xchb[2][256];
  __shared__ int rowcnt[2][4];
  __shared__ int cnd_gi[2][CAND_MAX];
  __shared__ int cnd_cnt[2];
  __shared__ int sh_list[2][32];
  __shared__ int sh_eq[2][96];
  __shared__ unsigned int sh_kmin[2];
  __shared__ int sh_ngt[2], sh_i33[2], sh_mx[2], sh_cnt[2], sh_ecnt[2];

  const int t = threadIdx.x, blk = blockIdx.x;
  const int p0 = blk * 2;
  const int b = p0 >> 12;
  const int row = t >> 7;
  const int col = t & 127;
  const int wid = t >> 6;
  const int sXor = col & 7;
  const float* xbp = xT + (size_t)b * NN * CC;
  const float* sqb = sqf + (size_t)b * NN;

  float4 xa[8], xb4[8];
  {
    const float4* r0 = (const float4*)(xT + (size_t)p0 * CC);
    const float4* r1 = (const float4*)(xT + (size_t)(p0 + 1) * CC);
#pragma unroll
    for (int j = 0; j < 8; ++j) { xa[j] = r0[8 * row + j]; xb4[j] = r1[8 * row + j]; }
  }
  const float srf = sqf[p0 + row];

  unsigned int keys32[32];

  auto stage = [&](int tt, float* xmb, float* sqmb) {
    const int m0s = tt << 7;
#pragma unroll
    for (int q = 0; q < 8; ++q) {
      int e = q * 256 + t;
      int c2 = e >> 4, slot = e & 15;
      const float4* gsrc = (const float4*)xbp + (((size_t)(m0s + c2)) << 4) + (slot ^ (c2 & 7));
      __builtin_amdgcn_global_load_lds(
          (const __attribute__((address_space(1))) void*)gsrc,
          (__attribute__((address_space(3))) void*)(xmb + (size_t)e * 4), 16, 0, 0);
    }
    if (t < 128)
      __builtin_amdgcn_global_load_lds(
          (const __attribute__((address_space(1))) void*)(sqb + m0s + t),
          (__attribute__((address_space(3))) void*)(sqmb + t), 4, 0, 0);
  };

  stage(0, xmT2[0], sqm2[0]);
  float pendA = 0.f, pendB = 0.f, pendSq = 0.f;
#pragma unroll
  for (int tile = 0; tile < 32; ++tile) {
    const int curb = tile & 1;
    asm volatile("s_waitcnt vmcnt(0)" ::: "memory");
    __syncthreads();
    if (tile > 0) {
      float other = xchb[(tile - 1) & 1][t ^ 128];
      float acc = (row == 0) ? (pendA + other) : (other + pendB);
      float dd = 2.0f * acc - srf;
      dd = dd - pendSq;
      keys32[tile - 1] = floatToKey(dd);
    }
    if (tile < 31) stage(tile + 1, xmT2[curb ^ 1], sqm2[curb ^ 1]);
    const float* xm = xmT2[curb];
    float pA = 0.f, pB = 0.f;
#pragma unroll
    for (int j = 0; j < 8; ++j) {
      int slot = (8 * row + j) ^ sXor;
      float4 mv = *(const float4*)&xm[col * 64 + slot * 4];
      pA = fmaf(xa[j].x, mv.x, pA); pA = fmaf(xa[j].y, mv.y, pA);
      pA = fmaf(xa[j].z, mv.z, pA); pA = fmaf(xa[j].w, mv.w, pA);
      pB = fmaf(xb4[j].x, mv.x, pB); pB = fmaf(xb4[j].y, mv.y, pB);
      pB = fmaf(xb4[j].z, mv.z, pB); pB = fmaf(xb4[j].w, mv.w, pB);
    }
    pendA = pA; pendB = pB; pendSq = sqm2[curb][col];
    xchb[tile & 1][t] = (row == 0) ? pB : pA;
  }
  __syncthreads();
  {
    float other = xchb[1][t ^ 128];
    float acc = (row == 0) ? (pendA + other) : (other + pendB);
    float dd = 2.0f * acc - srf;
    dd = dd - pendSq;
    keys32[31] = floatToKey(dd);
  }
  __syncthreads();
  if ((t & 127) == 0) cnd_cnt[row] = 0;

  unsigned int Pv = 0;
  int R = 33;
  for (int bit = 31; bit >= 0; --bit) {
    unsigned int tgt = (Pv >> bit) | 1u;
    int local = 0;
#pragma unroll
    for (int i = 0; i < 32; ++i) local += ((keys32[i] >> bit) == tgt) ? 1 : 0;
#pragma unroll
    for (int off = 32; off > 0; off >>= 1) local += __shfl_down(local, off, 64);
    if ((t & 63) == 0) rowcnt[bit & 1][wid] = local;
    __syncthreads();
    int c1 = rowcnt[bit & 1][row * 2] + rowcnt[bit & 1][row * 2 + 1];
    if (c1 >= R) Pv |= (1u << bit); else R -= c1;
  }
  const unsigned int thr = floatToKey(keyToFloat(Pv) - EPS2);

#pragma unroll
  for (int i = 0; i < 32; ++i) {
    if (keys32[i] >= thr) {
      int pos = atomicAdd(&cnd_cnt[row], 1);
      if (pos < CAND_MAX) cnd_gi[row][pos] = (i << 7) + col;
    }
  }
  __syncthreads();
  const int M = cnd_cnt[row] < CAND_MAX ? cnd_cnt[row] : CAND_MAX;

  {
    const float4* xrp = (const float4*)(xT + (size_t)(p0 + row) * CC);
#pragma unroll
    for (int j = 0; j < 8; ++j) { xa[j] = xrp[j]; xb4[j] = xrp[8 + j]; }
  }
  unsigned int ek0 = 0u, ek1 = 0u;
  int eg0 = -1, eg1 = -1;
  if (col < M) {
    int gi = cnd_gi[row][col];
    const float4* mp = (const float4*)&xbp[(size_t)gi * CC];
    double acc = 0.0;
#pragma unroll
    for (int cq = 0; cq < 8; ++cq) {
      float4 mv = mp[cq];
      acc += (double)xa[cq].x * (double)mv.x + (double)xa[cq].y * (double)mv.y +
             (double)xa[cq].z * (double)mv.z + (double)xa[cq].w * (double)mv.w;
    }
#pragma unroll
    for (int cq = 0; cq < 8; ++cq) {
      float4 mv = mp[8 + cq];
      acc += (double)xb4[cq].x * (double)mv.x + (double)xb4[cq].y * (double)mv.y +
             (double)xb4[cq].z * (double)mv.z + (double)xb4[cq].w * (double)mv.w;
    }
    float g = (float)acc;
    float d = 2.0f * g - srf;
    d = d - sqb[gi];
    ek0 = floatToKey(d);
    eg0 = gi;
  }
  if (col + 128 < M) {
    int gi = cnd_gi[row][col + 128];
    const float4* mp = (const float4*)&xbp[(size_t)gi * CC];
    double acc = 0.0;
#pragma unroll
    for (int cq = 0; cq < 8; ++cq) {
      float4 mv = mp[cq];
      acc += (double)xa[cq].x * (double)mv.x + (double)xa[cq].y * (double)mv.y +
             (double)xa[cq].z * (double)mv.z + (double)xa[cq].w * (double)mv.w;
    }
#pragma unroll
    for (int cq = 0; cq < 8; ++cq) {
      float4 mv = mp[8 + cq];
      acc += (double)xb4[cq].x * (double)mv.x + (double)xb4[cq].y * (double)mv.y +
             (double)xb4[cq].z * (double)mv.z + (double)xb4[cq].w * (double)mv.w;
    }
    float g = (float)acc;
    float d = 2.0f * g - srf;
    d = d - sqb[gi];
    ek1 = floatToKey(d);
    eg1 = gi;
  }

  Pv = 0;
  R = 33;
  for (int bit = 31; bit >= 0; --bit) {
    unsigned int tgt = (Pv >> bit) | 1u;
    int local = ((eg0 >= 0) && ((ek0 >> bit) == tgt)) +
                ((eg1 >= 0) && ((ek1 >> bit) == tgt));
#pragma unroll
    for (int off = 32; off > 0; off >>= 1) local += __shfl_down(local, off, 64);
    if ((t & 63) == 0) rowcnt[bit & 1][wid] = local;
    __syncthreads();
    int c1 = rowcnt[bit & 1][row * 2] + rowcnt[bit & 1][row * 2 + 1];
    if (c1 >= R) Pv |= (1u << bit); else R -= c1;
  }
  const unsigned int K33 = Pv;

  if ((t & 127) == 0) {
    sh_ngt[row] = 0; sh_kmin[row] = 0xffffffffu; sh_i33[row] = 0x7fffffff;
    sh_mx[row] = -1; sh_cnt[row] = 0; sh_ecnt[row] = 0;
  }
  __syncthreads();

  int ngt_loc = 0;
  unsigned int kmin_loc = 0xffffffffu;
  if (eg0 >= 0) {
    if (ek0 > K33) { ngt_loc++; kmin_loc = ek0 < kmin_loc ? ek0 : kmin_loc; }
    if (ek0 == K33) atomicMin(&sh_i33[row], eg0);
  }
  if (eg1 >= 0) {
    if (ek1 > K33) { ngt_loc++; kmin_loc = ek1 < kmin_loc ? ek1 : kmin_loc; }
    if (ek1 == K33) atomicMin(&sh_i33[row], eg1);
  }
  if (ngt_loc) { atomicAdd(&sh_ngt[row], ngt_loc); atomicMin(&sh_kmin[row], kmin_loc); }
  __syncthreads();

  const int ngt = sh_ngt[row];
  const unsigned int K32 = (ngt == 32) ? sh_kmin[row] : K33;
  if (eg0 >= 0) {
    if (ek0 > K33) { int pos = atomicAdd(&sh_cnt[row], 1); sh_list[row][pos] = eg0; }
    if (ngt == 32 && ek0 == K32) atomicMax(&sh_mx[row], eg0);
    if (ngt < 32 && ek0 == K33) { int pos = atomicAdd(&sh_ecnt[row], 1); if (pos < 96) sh_eq[row][pos] = eg0; }
  }
  if (eg1 >= 0) {
    if (ek1 > K33) { int pos = atomicAdd(&sh_cnt[row], 1); sh_list[row][pos] = eg1; }
    if (ngt == 32 && ek1 == K32) atomicMax(&sh_mx[row], eg1);
    if (ngt < 32 && ek1 == K33) { int pos = atomicAdd(&sh_ecnt[row], 1); if (pos < 96) sh_eq[row][pos] = eg1; }
  }
  __syncthreads();

  if ((t & 127) == 0) {
    const int p = p0 + row;
    if (ngt == 32) {
      int target = sh_mx[row], pos = 31;
      for (int q2 = 0; q2 < 32; ++q2) if (sh_list[row][q2] == target) pos = q2;
      int tmp = sh_list[row][31]; sh_list[row][31] = sh_list[row][pos]; sh_list[row][pos] = tmp;
      gapb[p] = __float_as_uint(__fsub_rn(keyToFloat(K32), keyToFloat(K33)));
      i33out[p] = sh_i33[row];
    } else {
      int ec = sh_ecnt[row]; if (ec > 96) ec = 96;
      for (int a = 1; a < ec; ++a) {
        int v = sh_eq[row][a]; int bp = a - 1;
        while (bp >= 0 && sh_eq[row][bp] > v) { sh_eq[row][bp + 1] = sh_eq[row][bp]; --bp; }
        sh_eq[row][bp + 1] = v;
      }
      int need = 32 - ngt;
      for (int a = 0; a < need; ++a) sh_list[row][ngt + a] = sh_eq[row][a];
      gapb[p] = 0x7f800000u;
      i33out[p] = (need < ec) ? sh_eq[row][need] : -1;
    }
  }
  __syncthreads();
  if (t < 64) {
    int rr = t >> 5, k = t & 31;
    idxout[(size_t)(p0 + rr) * KNN + k] = sh_list[rr][k];
  }
}

// ---------------- K2f: flip the globally smallest-positive-gap row --------
__global__ __launch_bounds__(256) void k2f_flip(
    const unsigned int* __restrict__ gapb, const int* __restrict__ i33,
    int* __restrict__ idxout) {
  __shared__ unsigned int sk[256];
  __shared__ int sv[256];
  const int t = threadIdx.x;
  unsigned int best = 0xffffffffu;
  int brow = -1;
  for (int i = t; i < BB * NN; i += 256) {
    unsigned int g = gapb[i];
    if (g < best) { best = g; brow = i; }
  }
  sk[t] = best; sv[t] = brow;
  __syncthreads();
  for (int s = 128; s > 0; s >>= 1) {
    if (t < s && sk[t + s] < sk[t]) { sk[t] = sk[t + s]; sv[t] = sv[t + s]; }
    __syncthreads();
  }
  if (t == 0 && sv[0] >= 0 && sk[0] > 0u && sk[0] < 0x7f800000u) {
    idxout[(size_t)sv[0] * KNN + 31] = i33[sv[0]];
  }
}

// ---------------- K3: gather h=base+P[idx], k-max/min + BN partials -------
__global__ __launch_bounds__(256) void k3_gather_stats(
    const float* __restrict__ Pm, const float* __restrict__ basem,
    const int* __restrict__ idxb, float* __restrict__ hmax,
    float* __restrict__ hmin, float* __restrict__ statsP) {
  const int t = threadIdx.x, blk = blockIdx.x;
  const int w = t >> 6, o = t & 63;
  float s1 = 0.f, s2 = 0.f;
#pragma unroll
  for (int q = 0; q < 4; ++q) {
    int p = blk * 16 + w * 4 + q;
    int b = p >> 12;
    const float* Pb = Pm + (size_t)b * NN * OO;
    float bse = basem[(size_t)p * OO + o];
    const int* ix = idxb + (size_t)p * KNN;
    float mx = -INFINITY, mn = INFINITY;
#pragma unroll 8
    for (int k = 0; k < KNN; ++k) {
      int i = ix[k];
      float h = bse + Pb[(size_t)i * OO + o];
      mx = fmaxf(mx, h);
      mn = fminf(mn, h);
      s1 += h;
      s2 = fmaf(h, h, s2);
    }
    hmax[(size_t)p * OO + o] = mx;
    hmin[(size_t)p * OO + o] = mn;
  }
  __shared__ float red[512];
  red[t] = s1; red[256 + t] = s2;
  __syncthreads();
  if (t < 64) {
    statsP[blk * 128 + t]      = red[t] + red[64 + t] + red[128 + t] + red[192 + t];
    statsP[blk * 128 + 64 + t] = red[256 + t] + red[320 + t] + red[384 + t] + red[448 + t];
  }
}

// ---------------- K4a: parallel partial reduction of statsP ---------------
__global__ __launch_bounds__(256) void k4a_partial(
    const float* __restrict__ statsP, float* __restrict__ part) {
  const int t = threadIdx.x, bi = blockIdx.x;
  const int col = t & 127, rg = t >> 7;  // rg 0/1
  float s = 0.f;
#pragma unroll
  for (int i = 0; i < 4; ++i)
    s += statsP[(bi * 8 + rg * 4 + i) * 128 + col];
  __shared__ float red[256];
  red[t] = s;
  __syncthreads();
  if (t < 128) part[bi * 128 + t] = red[t] + red[128 + t];
}

// ---------------- K4b: finalize BN scale/shift over 128 partials ----------
__global__ __launch_bounds__(256) void k4b_final(
    const float* __restrict__ part, const float* __restrict__ gamma,
    const float* __restrict__ beta, float* __restrict__ scsh) {
  __shared__ float red1[256], red2[256];
  const int t = threadIdx.x;
  const int o = t & 63, c = t >> 6;
  float s1 = 0.f, s2 = 0.f;
  for (int i = c; i < 128; i += 4) {
    s1 += part[i * 128 + o];
    s2 += part[i * 128 + 64 + o];
  }
  red1[t] = s1; red2[t] = s2;
  __syncthreads();
  if (t < 64) {
    s1 = red1[t] + red1[64 + t] + red1[128 + t] + red1[192 + t];
    s2 = red2[t] + red2[64 + t] + red2[128 + t] + red2[192 + t];
    const float inv = 1.0f / 524288.0f;
    float mean = s1 * inv;
    float var = s2 * inv - mean * mean;
    float r = rsqrtf(var + 1e-5f);
    float sc = gamma[t] * r;
    scsh[t] = sc;
    scsh[64 + t] = beta[t] - mean * sc;
  }
}

// ---------------- K5: epilogue: affine+relu on k-max/min, (B,O,N) --------
__global__ __launch_bounds__(256) void k5_epilogue(
    const float* __restrict__ hmax, const float* __restrict__ hmin,
    const float* __restrict__ scsh, float* __restrict__ out) {
  const int id = blockIdx.x * 256 + threadIdx.x;
  const int n = id & 4095, o = (id >> 12) & 63, b = id >> 18;
  float sc = scsh[o], sh = scsh[64 + o];
  size_t hoff = (((size_t)b << 12) + n) * OO + o;
  float H = (sc >= 0.f) ? hmax[hoff] : hmin[hoff];
  float y = sc * H + sh;
  out[id] = y > 0.f ? y : 0.f;
}

extern "C" void kernel_launch(void* const* d_in, const int* in_sizes, int n_in,
                              void* d_out, int out_size, void* d_ws, size_t ws_size,
                              hipStream_t stream) {
  const float* pts   = (const float*)d_in[0];
  const float* W     = (const float*)d_in[1];
  const float* gamma = (const float*)d_in[2];
  const float* beta  = (const float*)d_in[3];
  float* outp = (float*)d_out;
  float* wsf = (float*)d_ws;

  float*          xT    = wsf + XT_OFF;
  float*          sqf   = wsf + SQ_OFF;
  float*          P     = wsf + P_OFF;
  float*          base  = wsf + BASE_OFF;
  float*          hmax  = wsf + HMAX_OFF;
  float*          hmin  = wsf + HMIN_OFF;
  float*          stats = wsf + STATS_OFF;
  float*          scsh  = wsf + SCSH_OFF;
  int*            idx   = (int*)(wsf + IDX_OFF);
  unsigned int*   gapb  = (unsigned int*)(wsf + GAP_OFF);
  int*            i33   = (int*)(wsf + I33_OFF);
  // xh/xl alias hmax/hmin regions (disjoint lifetimes: k1->k2m vs k3->k5)
  unsigned short* xh    = (unsigned short*)(wsf + HMAX_OFF);
  unsigned short* xl    = (unsigned short*)(wsf + HMIN_OFF);
  float*          part  = wsf + P_OFF;   // P region dead after k3

  k1_transpose_sq<<<256, 256, 0, stream>>>(pts, xT, sqf, xh, xl);
  k2b_small_gemm<<<256, 256, 0, stream>>>(xT, W, P, base);

  const int split = (ws_size >= (size_t)(KEYS_OFF + (size_t)NN * NN) * 4u);
  if (split) {
    unsigned int* keysu = (unsigned int*)(wsf + KEYS_OFF);
    for (int b = 0; b < BB; ++b) {
      k2m_mfma_screen<<<1024, 256, 0, stream>>>(
          xh + (size_t)b * NN * CC, xl + (size_t)b * NN * CC,
          sqf + (size_t)b * NN, keysu);
      k2sel<<<1024, 256, 0, stream>>>(
          keysu, xT + (size_t)b * NN * CC, sqf + (size_t)b * NN,
          idx + (size_t)b * NN * KNN, gapb + (size_t)b * NN,
          i33 + (size_t)b * NN);
    }
  } else {
    k2_gram_select<<<8192, 256, 0, stream>>>(xT, sqf, idx, gapb, i33);
  }
  k2f_flip<<<1, 256, 0, stream>>>(gapb, i33, idx);
  k3_gather_stats<<<1024, 256, 0, stream>>>(P, base, idx, hmax, hmin, stats);
  k4a_partial<<<128, 256, 0, stream>>>(stats, part);
  k4b_final<<<1, 256, 0, stream>>>(part, gamma, beta, scsh);
  k5_epilogue<<<4096, 256, 0, stream>>>(hmax, hmin, scsh, outp);
}

// Round 18
// 417.139 us; speedup vs baseline: 1.1200x; 1.0648x over previous
//
#include <hip/hip_runtime.h>
#include <math.h>

#define BB 4
#define CC 64
#define NN 4096
#define OO 64
#define KNN 32
#define CAND_MAX 192
#define EPS2 0.0625f

// ws layout (float offsets) — base footprint 23.66 MB; split path total
// 57.2 MB (< 90.8 MB R3/R9-proven). xh/xl ALIAS hmax/hmin (disjoint
// lifetimes: xh/xl live k1->k2m; hmax/hmin live k3->k5).
#define XT_OFF    0u          // (B,N,C) fp32          1048576
#define SQ_OFF    1048576u    // (B,N) fp32             16384
#define P_OFF     1064960u    // (B,N,O)               1048576
#define BASE_OFF  2113536u    // (B,N,O)               1048576
#define HMAX_OFF  3162112u    // (B,N,O)               1048576  (k1-k2m: xh)
#define HMIN_OFF  4210688u    // (B,N,O)               1048576  (k1-k2m: xl)
#define STATS_OFF 5259264u    // 1024 x 128            131072
#define SCSH_OFF  5390336u    // 128
#define IDX_OFF   5390464u    // (B,N,K) int32         524288
// gap/i33 overlay the stats region (disjoint lifetimes: k2/k2f before k3)
#define GAP_OFF   5259264u    // (B*N) uint            16384
#define I33_OFF   5275648u    // (B*N) int              16384
// 16-bit screen-key prefixes (split path): one batch (N,N) ushort = 33.5MB
#define KEYS_OFF  5914752u    // (N,N) ushort          8388608 floats

typedef short bf16x8 __attribute__((ext_vector_type(8)));
typedef float f32x4 __attribute__((ext_vector_type(4)));

__device__ __forceinline__ float keyToFloat(unsigned int u) {
  unsigned int b = (u & 0x80000000u) ? (u & 0x7fffffffu) : ~u;
  return __uint_as_float(b);
}
__device__ __forceinline__ unsigned int floatToKey(float f) {
  unsigned int bb = __float_as_uint(f);
  return (bb & 0x80000000u) ? ~bb : (bb | 0x80000000u);
}
__device__ __forceinline__ unsigned short f2bf(float f) {
  unsigned u = __float_as_uint(f);
  unsigned r = ((u >> 16) & 1u) + 0x7fffu;  // RNE
  return (unsigned short)((u + r) >> 16);
}
__device__ __forceinline__ float bf2f(unsigned short h) {
  return __uint_as_float(((unsigned)h) << 16);
}
// load 8 floats at p, split into hi/lo bf16 fragments (fallback path only)
__device__ __forceinline__ void split8(const float* p, bf16x8& h, bf16x8& l) {
  float4 a = *(const float4*)p;
  float4 b = *(const float4*)(p + 4);
  float v[8] = {a.x, a.y, a.z, a.w, b.x, b.y, b.z, b.w};
#pragma unroll
  for (int e = 0; e < 8; ++e) {
    unsigned short hh = f2bf(v[e]);
    h[e] = (short)hh;
    l[e] = (short)f2bf(v[e] - bf2f(hh));
  }
}
// wave-wide sums via ballots — no DS-pipe ops
__device__ __forceinline__ int waveSum7(int local) {
  int s = 0;
#pragma unroll
  for (int b = 0; b < 7; ++b)
    s += (int)__popcll(__ballot((local >> b) & 1)) << b;
  return s;
}
__device__ __forceinline__ int waveSum2(int local) {
  int s = (int)__popcll(__ballot(local & 1));
  s += (int)__popcll(__ballot((local >> 1) & 1)) << 1;
  return s;
}

// ---------------- K1: transpose + sq + precomputed bf16 hi/lo split -------
__global__ __launch_bounds__(256) void k1_transpose_sq(
    const float* __restrict__ pts, float* __restrict__ xT, float* __restrict__ sqf,
    unsigned short* __restrict__ xh, unsigned short* __restrict__ xl) {
  __shared__ float tile[64 * 65];
  __shared__ double sqp[256];
  const int t = threadIdx.x, blk = blockIdx.x;
  const int b = blk >> 6, n0 = (blk & 63) << 6;
  const float* pb = pts + (size_t)b * CC * NN;
  const int j = t & 63, cg = t >> 6;
  double acc = 0.0;
#pragma unroll
  for (int i = 0; i < 16; ++i) {
    int c = cg * 16 + i;
    float v = pb[(size_t)c * NN + n0 + j];
    tile[c * 65 + j] = v;
    acc += (double)v * (double)v;
  }
  sqp[t] = acc;
  __syncthreads();
  const int c2 = t & 63, jg = t >> 6;
#pragma unroll
  for (int i = 0; i < 16; ++i) {
    int jj = jg * 16 + i;
    float vv = tile[c2 * 65 + jj];
    size_t xoff = ((size_t)b * NN + n0 + jj) * CC + c2;
    xT[xoff] = vv;
    unsigned short hh = f2bf(vv);
    xh[xoff] = hh;
    xl[xoff] = f2bf(vv - bf2f(hh));
  }
  if (t < 64)
    sqf[b * NN + n0 + t] = (float)(sqp[t] + sqp[64 + t] + sqp[128 + t] + sqp[192 + t]);
}

// ---------------- K2b: P = x.w2^T, base = x.(w1-w2)^T ---------------------
__global__ __launch_bounds__(256) void k2b_small_gemm(
    const float* __restrict__ xT, const float* __restrict__ W,
    float* __restrict__ P, float* __restrict__ base) {
  __shared__ float w2T[64 * 65];
  __shared__ float wdT[64 * 65];
  __shared__ float xbuf[4 * 64];
  const int t = threadIdx.x, blk = blockIdx.x;
  const int b = blk >> 6, n0 = (blk & 63) << 6;
#pragma unroll
  for (int i = 0; i < 16; ++i) {
    int e = i * 256 + t, o = e >> 6, c = e & 63;
    w2T[c * 65 + o] = W[o * 128 + 64 + c];
  }
  __syncthreads();
#pragma unroll
  for (int i = 0; i < 16; ++i) {
    int e = i * 256 + t, o = e >> 6, c = e & 63;
    wdT[c * 65 + o] = W[o * 128 + c] - w2T[c * 65 + o];
  }
  __syncthreads();
  const int w = t >> 6, lane = t & 63;
  for (int it = 0; it < 16; ++it) {
    int n = n0 + it * 4 + w;
    xbuf[t] = xT[((size_t)b * NN + n) * CC + lane];
    __syncthreads();
    float accP = 0.f, accB = 0.f;
#pragma unroll
    for (int c = 0; c < 64; ++c) {
      float xc = xbuf[w * 64 + c];
      accP = fmaf(xc, w2T[c * 65 + lane], accP);
      accB = fmaf(xc, wdT[c * 65 + lane], accB);
    }
    size_t off = ((size_t)b * NN + n) * OO + lane;
    P[off] = accP;
    base[off] = accB;
    __syncthreads();
  }
}

// ---------------- K2m: MFMA screen -> 16-bit key prefixes -----------------
// R13-measured: 16-bit key writes make k2m faster (write traffic halved);
// the R13 k2sel slowdown was the 6-slot inflation, removed this round.
__global__ __launch_bounds__(256) void k2m_mfma_screen(
    const unsigned short* __restrict__ xhb, const unsigned short* __restrict__ xlb,
    const float* __restrict__ sqb, unsigned short* __restrict__ keys16) {
  const int t = threadIdx.x, blk = blockIdx.x;
  const int stripe = blk >> 3;   // rows stripe*32..+31
  const int chunk = blk & 7;     // cols chunk*512..+511
  const int wid = t >> 6, l = t & 63;
  const int r0 = stripe * 32;
  const int cbase = chunk * 512 + wid * 128;
  const int i16 = l & 15, kb = l >> 4;

  bf16x8 ah[2][2], al[2][2];
#pragma unroll
  for (int rt = 0; rt < 2; ++rt) {
    size_t rb = (size_t)(r0 + rt * 16 + i16) * CC + kb * 8;
#pragma unroll
    for (int kc = 0; kc < 2; ++kc) {
      ah[rt][kc] = *(const bf16x8*)&xhb[rb + kc * 32];
      al[rt][kc] = *(const bf16x8*)&xlb[rb + kc * 32];
    }
  }
  float srow[2][4];
#pragma unroll
  for (int rt = 0; rt < 2; ++rt)
#pragma unroll
    for (int v = 0; v < 4; ++v)
      srow[rt][v] = sqb[r0 + rt * 16 + kb * 4 + v];

  for (int ct = 0; ct < 8; ++ct) {
    const int colg = cbase + ct * 16 + i16;
    bf16x8 bh[2], bl[2];
    size_t cb = (size_t)colg * CC + kb * 8;
#pragma unroll
    for (int kc = 0; kc < 2; ++kc) {
      bh[kc] = *(const bf16x8*)&xhb[cb + kc * 32];
      bl[kc] = *(const bf16x8*)&xlb[cb + kc * 32];
    }
    const float sqc = sqb[colg];
#pragma unroll
    for (int rt = 0; rt < 2; ++rt) {
      f32x4 acc = {0.f, 0.f, 0.f, 0.f};
#pragma unroll
      for (int kc = 0; kc < 2; ++kc) {
        acc = __builtin_amdgcn_mfma_f32_16x16x32_bf16(ah[rt][kc], bh[kc], acc, 0, 0, 0);
        acc = __builtin_amdgcn_mfma_f32_16x16x32_bf16(ah[rt][kc], bl[kc], acc, 0, 0, 0);
        acc = __builtin_amdgcn_mfma_f32_16x16x32_bf16(al[rt][kc], bh[kc], acc, 0, 0, 0);
      }
      const int rowb = r0 + rt * 16 + kb * 4;
#pragma unroll
      for (int v = 0; v < 4; ++v) {
        float d = 2.0f * acc[v] - srow[rt][v] - sqc;
        keys16[(size_t)(rowb + v) * NN + colg] =
            (unsigned short)(floatToKey(d) >> 16);
      }
    }
  }
}

// ---------------- K2sel: per-wave select on 16-bit prefixes, 3 slots ------
// = R13's verified packed-prefix load + phase 2/3, but with R16's verified
// 3-slot/CAND_MAX=192 phases 4/5 (R13's 6 slots were unneeded: prefix
// window widens by <=1 ulp16 ~ 0.7 at |d|~80; key density ~5/unit near the
// 33rd -> expected M ~ 40 << 192). Phase 4 streams the row vector per
// candidate (memory clobber stops cross-candidate hoisting) instead of
// pinning 64 VGPRs; dot summation order identical -> bit-stable exact keys.
__global__ __launch_bounds__(256) void k2sel(
    const unsigned short* __restrict__ keysb, const float* __restrict__ xbp,
    const float* __restrict__ sqb, int* __restrict__ idxout,
    unsigned int* __restrict__ gapb, int* __restrict__ i33out) {
  __shared__ int cnd_gi[4][CAND_MAX];
  __shared__ int cnd_cnt[4];
  __shared__ int sh_list[4][32];
  __shared__ int sh_eq[4][96];
  __shared__ unsigned int sh_kmin[4];
  __shared__ int sh_ngt[4], sh_i33[4], sh_mx[4], sh_cnt[4], sh_ecnt[4];

  const int t = threadIdx.x, blk = blockIdx.x;
  const int v = t >> 6, l = t & 63;
  const int p = blk * 4 + v;  // this wave's row
  const float srf = sqb[p];

  // 64 key-prefixes/thread: uint4 q covers ushorts gi = q*512 + l*8 .. +7
  uint4 kq[8];
  {
    const uint4* kp = (const uint4*)(keysb + (size_t)p * NN);
#pragma unroll
    for (int q = 0; q < 8; ++q) kq[q] = kp[q * 64 + l];
  }
  if (l == 0) {
    cnd_cnt[v] = 0;
    sh_ngt[v] = 0; sh_kmin[v] = 0xffffffffu; sh_i33[v] = 0x7fffffff;
    sh_mx[v] = -1; sh_cnt[v] = 0; sh_ecnt[v] = 0;
  }
  __syncthreads();

  // ---- phase 2: binary search on 16-bit prefixes (ballot-counted) --------
  unsigned int Pv = 0;
  int R = 33;
  for (int bit = 15; bit >= 0; --bit) {
    unsigned int tgt = (Pv >> bit) | 1u;
    int local = 0;
#pragma unroll
    for (int q = 0; q < 8; ++q) {
      uint4 kv = kq[q];
      unsigned int us[4] = {kv.x, kv.y, kv.z, kv.w};
#pragma unroll
      for (int j = 0; j < 4; ++j) {
        unsigned int lo = us[j] & 0xffffu, hi = us[j] >> 16;
        local += ((lo >> bit) == tgt) + ((hi >> bit) == tgt);
      }
    }
    int c1 = waveSum7(local);
    if (c1 >= R) Pv |= (1u << bit); else R -= c1;
  }
  const float v33q = keyToFloat(Pv << 16);   // <= s(33) in float order
  const unsigned int thr16 = floatToKey(v33q - EPS2) >> 16;

  // ---- phase 3: collect candidates (prefix >= thr16) ---------------------
#pragma unroll
  for (int q = 0; q < 8; ++q) {
    uint4 kv = kq[q];
    unsigned int us[4] = {kv.x, kv.y, kv.z, kv.w};
#pragma unroll
    for (int j = 0; j < 4; ++j) {
      unsigned int lo = us[j] & 0xffffu, hi = us[j] >> 16;
      int gib = q * 512 + l * 8 + 2 * j;
      if (lo >= thr16) {
        int pos = atomicAdd(&cnd_cnt[v], 1);
        if (pos < CAND_MAX) cnd_gi[v][pos] = gib;
      }
      if (hi >= thr16) {
        int pos = atomicAdd(&cnd_cnt[v], 1);
        if (pos < CAND_MAX) cnd_gi[v][pos] = gib + 1;
      }
    }
  }
  __syncthreads();
  const int M = cnd_cnt[v] < CAND_MAX ? cnd_cnt[v] : CAND_MAX;

  // ---- phase 4: exact fp64-round-once keys (<=3 candidates/lane) ---------
  unsigned int ek[3] = {0u, 0u, 0u};
  int eg[3] = {-1, -1, -1};
  {
    const float4* rp = (const float4*)(xbp + (size_t)p * CC);
#pragma unroll
    for (int c3 = 0; c3 < 3; ++c3) {
      int ci = l + 64 * c3;
      if (ci < M) {
        int gi = cnd_gi[v][ci];
        const float4* mp = (const float4*)&xbp[(size_t)gi * CC];
        double acc = 0.0;
#pragma unroll
        for (int cq = 0; cq < 16; ++cq) {
          float4 rv = rp[cq];
          float4 mv = mp[cq];
          acc += (double)rv.x * (double)mv.x + (double)rv.y * (double)mv.y +
                 (double)rv.z * (double)mv.z + (double)rv.w * (double)mv.w;
        }
        float g = (float)acc;    // fp64 dot rounded once to fp32
        float d = 2.0f * g - srf;
        d = d - sqb[gi];
        ek[c3] = floatToKey(d);
        eg[c3] = gi;
      }
      asm volatile("" ::: "memory");  // no cross-candidate load hoisting
    }
  }

  // ---- phase 5: exact K33 binary search over candidates (ballot) ---------
  unsigned int Pe = 0;
  R = 33;
  for (int bit = 31; bit >= 0; --bit) {
    unsigned int tgt = (Pe >> bit) | 1u;
    int local = 0;
#pragma unroll
    for (int c3 = 0; c3 < 3; ++c3)
      local += (eg[c3] >= 0) && ((ek[c3] >> bit) == tgt);
    int c1 = waveSum2(local);
    if (c1 >= R) Pe |= (1u << bit); else R -= c1;
  }
  const unsigned int K33 = Pe;

  int ngt_loc = 0;
  unsigned int kmin_loc = 0xffffffffu;
#pragma unroll
  for (int c3 = 0; c3 < 3; ++c3) {
    if (eg[c3] >= 0) {
      if (ek[c3] > K33) { ngt_loc++; kmin_loc = ek[c3] < kmin_loc ? ek[c3] : kmin_loc; }
      if (ek[c3] == K33) atomicMin(&sh_i33[v], eg[c3]);
    }
  }
  if (ngt_loc) { atomicAdd(&sh_ngt[v], ngt_loc); atomicMin(&sh_kmin[v], kmin_loc); }
  __syncthreads();

  const int ngt = sh_ngt[v];
  const unsigned int K32 = (ngt == 32) ? sh_kmin[v] : K33;
#pragma unroll
  for (int c3 = 0; c3 < 3; ++c3) {
    if (eg[c3] >= 0) {
      if (ek[c3] > K33) { int pos = atomicAdd(&sh_cnt[v], 1); sh_list[v][pos] = eg[c3]; }
      if (ngt == 32 && ek[c3] == K32) atomicMax(&sh_mx[v], eg[c3]);
      if (ngt < 32 && ek[c3] == K33) { int pos = atomicAdd(&sh_ecnt[v], 1); if (pos < 96) sh_eq[v][pos] = eg[c3]; }
    }
  }
  __syncthreads();

  if (l == 0) {
    if (ngt == 32) {
      int target = sh_mx[v], pos = 31;
      for (int q2 = 0; q2 < 32; ++q2) if (sh_list[v][q2] == target) pos = q2;
      int tmp = sh_list[v][31]; sh_list[v][31] = sh_list[v][pos]; sh_list[v][pos] = tmp;
      gapb[p] = __float_as_uint(__fsub_rn(keyToFloat(K32), keyToFloat(K33)));
      i33out[p] = sh_i33[v];
    } else {
      int ec = sh_ecnt[v]; if (ec > 96) ec = 96;
      for (int a = 1; a < ec; ++a) {
        int vv = sh_eq[v][a]; int bp = a - 1;
        while (bp >= 0 && sh_eq[v][bp] > vv) { sh_eq[v][bp + 1] = sh_eq[v][bp]; --bp; }
        sh_eq[v][bp + 1] = vv;
      }
      int need = 32 - ngt;
      for (int a = 0; a < need; ++a) sh_list[v][ngt + a] = sh_eq[v][a];
      gapb[p] = 0x7f800000u;
      i33out[p] = (need < ec) ? sh_eq[v][need] : -1;
    }
  }
  __syncthreads();
  if (l < 32) idxout[(size_t)p * KNN + l] = sh_list[v][l];
}

// ---------------- K2 (fallback, R8-verified): fused screen+select ---------
__global__ __launch_bounds__(256, 2) void k2_gram_select(
    const float* __restrict__ xT, const float* __restrict__ sqf,
    int* __restrict__ idxout, unsigned int* __restrict__ gapb,
    int* __restrict__ i33out) {
  __shared__ __align__(16) float xmT2[2][8192];
  __shared__ float sqm2[2][128];
  __shared__ float xchb[2][256];
  __shared__ int rowcnt[2][4];
  __shared__ int cnd_gi[2][CAND_MAX];
  __shared__ int cnd_cnt[2];
  __shared__ int sh_list[2][32];
  __shared__ int sh_eq[2][96];
  __shared__ unsigned int sh_kmin[2];
  __shared__ int sh_ngt[2], sh_i33[2], sh_mx[2], sh_cnt[2], sh_ecnt[2];

  const int t = threadIdx.x, blk = blockIdx.x;
  const int p0 = blk * 2;
  const int b = p0 >> 12;
  const int row = t >> 7;
  const int col = t & 127;
  const int wid = t >> 6;
  const int sXor = col & 7;
  const float* xbp = xT + (size_t)b * NN * CC;
  const float* sqb = sqf + (size_t)b * NN;

  float4 xa[8], xb4[8];
  {
    const float4* r0 = (const float4*)(xT + (size_t)p0 * CC);
    const float4* r1 = (const float4*)(xT + (size_t)(p0 + 1) * CC);
#pragma unroll
    for (int j = 0; j < 8; ++j) { xa[j] = r0[8 * row + j]; xb4[j] = r1[8 * row + j]; }
  }
  const float srf = sqf[p0 + row];

  unsigned int keys32[32];

  auto stage = [&](int tt, float* xmb, float* sqmb) {
    const int m0s = tt << 7;
#pragma unroll
    for (int q = 0; q < 8; ++q) {
      int e = q * 256 + t;
      int c2 = e >> 4, slot = e & 15;
      const float4* gsrc = (const float4*)xbp + (((size_t)(m0s + c2)) << 4) + (slot ^ (c2 & 7));
      __builtin_amdgcn_global_load_lds(
          (const __attribute__((address_space(1))) void*)gsrc,
          (__attribute__((address_space(3))) void*)(xmb + (size_t)e * 4), 16, 0, 0);
    }
    if (t < 128)
      __builtin_amdgcn_global_load_lds(
          (const __attribute__((address_space(1))) void*)(sqb + m0s + t),
          (__attribute__((address_space(3))) void*)(sqmb + t), 4, 0, 0);
  };

  stage(0, xmT2[0], sqm2[0]);
  float pendA = 0.f, pendB = 0.f, pendSq = 0.f;
#pragma unroll
  for (int tile = 0; tile < 32; ++tile) {
    const int curb = tile & 1;
    asm volatile("s_waitcnt vmcnt(0)" ::: "memory");
    __syncthreads();
    if (tile > 0) {
      float other = xchb[(tile - 1) & 1][t ^ 128];
      float acc = (row == 0) ? (pendA + other) : (other + pendB);
      float dd = 2.0f * acc - srf;
      dd = dd - pendSq;
      keys32[tile - 1] = floatToKey(dd);
    }
    if (tile < 31) stage(tile + 1, xmT2[curb ^ 1], sqm2[curb ^ 1]);
    const float* xm = xmT2[curb];
    float pA = 0.f, pB = 0.f;
#pragma unroll
    for (int j = 0; j < 8; ++j) {
      int slot = (8 * row + j) ^ sXor;
      float4 mv = *(const float4*)&xm[col * 64 + slot * 4];
      pA = fmaf(xa[j].x, mv.x, pA); pA = fmaf(xa[j].y, mv.y, pA);
      pA = fmaf(xa[j].z, mv.z, pA); pA = fmaf(xa[j].w, mv.w, pA);
      pB = fmaf(xb4[j].x, mv.x, pB); pB = fmaf(xb4[j].y, mv.y, pB);
      pB = fmaf(xb4[j].z, mv.z, pB); pB = fmaf(xb4[j].w, mv.w, pB);
    }
    pendA = pA; pendB = pB; pendSq = sqm2[curb][col];
    xchb[tile & 1][t] = (row == 0) ? pB : pA;
  }
  __syncthreads();
  {
    float other = xchb[1][t ^ 128];
    float acc = (row == 0) ? (pendA + other) : (other + pendB);
    float dd = 2.0f * acc - srf;
    dd = dd - pendSq;
    keys32[31] = floatToKey(dd);
  }
  __syncthreads();
  if ((t & 127) == 0) cnd_cnt[row] = 0;

  unsigned int Pv = 0;
  int R = 33;
  for (int bit = 31; bit >= 0; --bit) {
    unsigned int tgt = (Pv >> bit) | 1u;
    int local = 0;
#pragma unroll
    for (int i = 0; i < 32; ++i) local += ((keys32[i] >> bit) == tgt) ? 1 : 0;
#pragma unroll
    for (int off = 32; off > 0; off >>= 1) local += __shfl_down(local, off, 64);
    if ((t & 63) == 0) rowcnt[bit & 1][wid] = local;
    __syncthreads();
    int c1 = rowcnt[bit & 1][row * 2] + rowcnt[bit & 1][row * 2 + 1];
    if (c1 >= R) Pv |= (1u << bit); else R -= c1;
  }
  const unsigned int thr = floatToKey(keyToFloat(Pv) - EPS2);

#pragma unroll
  for (int i = 0; i < 32; ++i) {
    if (keys32[i] >= thr) {
      int pos = atomicAdd(&cnd_cnt[row], 1);
      if (pos < CAND_MAX) cnd_gi[row][pos] = (i << 7) + col;
    }
  }
  __syncthreads();
  const int M = cnd_cnt[row] < CAND_MAX ? cnd_cnt[row] : CAND_MAX;

  {
    const float4* xrp = (const float4*)(xT + (size_t)(p0 + row) * CC);
#pragma unroll
    for (int j = 0; j < 8; ++j) { xa[j] = xrp[j]; xb4[j] = xrp[8 + j]; }
  }
  unsigned int ek0 = 0u, ek1 = 0u;
  int eg0 = -1, eg1 = -1;
  if (col < M) {
    int gi = cnd_gi[row][col];
    const float4* mp = (const float4*)&xbp[(size_t)gi * CC];
    double acc = 0.0;
#pragma unroll
    for (int cq = 0; cq < 8; ++cq) {
      float4 mv = mp[cq];
      acc += (double)xa[cq].x * (double)mv.x + (double)xa[cq].y * (double)mv.y +
             (double)xa[cq].z * (double)mv.z + (double)xa[cq].w * (double)mv.w;
    }
#pragma unroll
    for (int cq = 0; cq < 8; ++cq) {
      float4 mv = mp[8 + cq];
      acc += (double)xb4[cq].x * (double)mv.x + (double)xb4[cq].y * (double)mv.y +
             (double)xb4[cq].z * (double)mv.z + (double)xb4[cq].w * (double)mv.w;
    }
    float g = (float)acc;
    float d = 2.0f * g - srf;
    d = d - sqb[gi];
    ek0 = floatToKey(d);
    eg0 = gi;
  }
  if (col + 128 < M) {
    int gi = cnd_gi[row][col + 128];
    const float4* mp = (const float4*)&xbp[(size_t)gi * CC];
    double acc = 0.0;
#pragma unroll
    for (int cq = 0; cq < 8; ++cq) {
      float4 mv = mp[cq];
      acc += (double)xa[cq].x * (double)mv.x + (double)xa[cq].y * (double)mv.y +
             (double)xa[cq].z * (double)mv.z + (double)xa[cq].w * (double)mv.w;
    }
#pragma unroll
    for (int cq = 0; cq < 8; ++cq) {
      float4 mv = mp[8 + cq];
      acc += (double)xb4[cq].x * (double)mv.x + (double)xb4[cq].y * (double)mv.y +
             (double)xb4[cq].z * (double)mv.z + (double)xb4[cq].w * (double)mv.w;
    }
    float g = (float)acc;
    float d = 2.0f * g - srf;
    d = d - sqb[gi];
    ek1 = floatToKey(d);
    eg1 = gi;
  }

  Pv = 0;
  R = 33;
  for (int bit = 31; bit >= 0; --bit) {
    unsigned int tgt = (Pv >> bit) | 1u;
    int local = ((eg0 >= 0) && ((ek0 >> bit) == tgt)) +
                ((eg1 >= 0) && ((ek1 >> bit) == tgt));
#pragma unroll
    for (int off = 32; off > 0; off >>= 1) local += __shfl_down(local, off, 64);
    if ((t & 63) == 0) rowcnt[bit & 1][wid] = local;
    __syncthreads();
    int c1 = rowcnt[bit & 1][row * 2] + rowcnt[bit & 1][row * 2 + 1];
    if (c1 >= R) Pv |= (1u << bit); else R -= c1;
  }
  const unsigned int K33 = Pv;

  if ((t & 127) == 0) {
    sh_ngt[row] = 0; sh_kmin[row] = 0xffffffffu; sh_i33[row] = 0x7fffffff;
    sh_mx[row] = -1; sh_cnt[row] = 0; sh_ecnt[row] = 0;
  }
  __syncthreads();

  int ngt_loc = 0;
  unsigned int kmin_loc = 0xffffffffu;
  if (eg0 >= 0) {
    if (ek0 > K33) { ngt_loc++; kmin_loc = ek0 < kmin_loc ? ek0 : kmin_loc; }
    if (ek0 == K33) atomicMin(&sh_i33[row], eg0);
  }
  if (eg1 >= 0) {
    if (ek1 > K33) { ngt_loc++; kmin_loc = ek1 < kmin_loc ? ek1 : kmin_loc; }
    if (ek1 == K33) atomicMin(&sh_i33[row], eg1);
  }
  if (ngt_loc) { atomicAdd(&sh_ngt[row], ngt_loc); atomicMin(&sh_kmin[row], kmin_loc); }
  __syncthreads();

  const int ngt = sh_ngt[row];
  const unsigned int K32 = (ngt == 32) ? sh_kmin[row] : K33;
  if (eg0 >= 0) {
    if (ek0 > K33) { int pos = atomicAdd(&sh_cnt[row], 1); sh_list[row][pos] = eg0; }
    if (ngt == 32 && ek0 == K32) atomicMax(&sh_mx[row], eg0);
    if (ngt < 32 && ek0 == K33) { int pos = atomicAdd(&sh_ecnt[row], 1); if (pos < 96) sh_eq[row][pos] = eg0; }
  }
  if (eg1 >= 0) {
    if (ek1 > K33) { int pos = atomicAdd(&sh_cnt[row], 1); sh_list[row][pos] = eg1; }
    if (ngt == 32 && ek1 == K32) atomicMax(&sh_mx[row], eg1);
    if (ngt < 32 && ek1 == K33) { int pos = atomicAdd(&sh_ecnt[row], 1); if (pos < 96) sh_eq[row][pos] = eg1; }
  }
  __syncthreads();

  if ((t & 127) == 0) {
    const int p = p0 + row;
    if (ngt == 32) {
      int target = sh_mx[row], pos = 31;
      for (int q2 = 0; q2 < 32; ++q2) if (sh_list[row][q2] == target) pos = q2;
      int tmp = sh_list[row][31]; sh_list[row][31] = sh_list[row][pos]; sh_list[row][pos] = tmp;
      gapb[p] = __float_as_uint(__fsub_rn(keyToFloat(K32), keyToFloat(K33)));
      i33out[p] = sh_i33[row];
    } else {
      int ec = sh_ecnt[row]; if (ec > 96) ec = 96;
      for (int a = 1; a < ec; ++a) {
        int v = sh_eq[row][a]; int bp = a - 1;
        while (bp >= 0 && sh_eq[row][bp] > v) { sh_eq[row][bp + 1] = sh_eq[row][bp]; --bp; }
        sh_eq[row][bp + 1] = v;
      }
      int need = 32 - ngt;
      for (int a = 0; a < need; ++a) sh_list[row][ngt + a] = sh_eq[row][a];
      gapb[p] = 0x7f800000u;
      i33out[p] = (need < ec) ? sh_eq[row][need] : -1;
    }
  }
  __syncthreads();
  if (t < 64) {
    int rr = t >> 5, k = t & 31;
    idxout[(size_t)(p0 + rr) * KNN + k] = sh_list[rr][k];
  }
}

// ---------------- K2f: flip the globally smallest-positive-gap row --------
__global__ __launch_bounds__(256) void k2f_flip(
    const unsigned int* __restrict__ gapb, const int* __restrict__ i33,
    int* __restrict__ idxout) {
  __shared__ unsigned int sk[256];
  __shared__ int sv[256];
  const int t = threadIdx.x;
  unsigned int best = 0xffffffffu;
  int brow = -1;
  for (int i = t; i < BB * NN; i += 256) {
    unsigned int g = gapb[i];
    if (g < best) { best = g; brow = i; }
  }
  sk[t] = best; sv[t] = brow;
  __syncthreads();
  for (int s = 128; s > 0; s >>= 1) {
    if (t < s && sk[t + s] < sk[t]) { sk[t] = sk[t + s]; sv[t] = sv[t + s]; }
    __syncthreads();
  }
  if (t == 0 && sv[0] >= 0 && sk[0] > 0u && sk[0] < 0x7f800000u) {
    idxout[(size_t)sv[0] * KNN + 31] = i33[sv[0]];
  }
}

// ---------------- K3: gather h=base+P[idx], k-max/min + BN partials -------
__global__ __launch_bounds__(256) void k3_gather_stats(
    const float* __restrict__ Pm, const float* __restrict__ basem,
    const int* __restrict__ idxb, float* __restrict__ hmax,
    float* __restrict__ hmin, float* __restrict__ statsP) {
  const int t = threadIdx.x, blk = blockIdx.x;
  const int w = t >> 6, o = t & 63;
  float s1 = 0.f, s2 = 0.f;
#pragma unroll
  for (int q = 0; q < 4; ++q) {
    int p = blk * 16 + w * 4 + q;
    int b = p >> 12;
    const float* Pb = Pm + (size_t)b * NN * OO;
    float bse = basem[(size_t)p * OO + o];
    const int* ix = idxb + (size_t)p * KNN;
    float mx = -INFINITY, mn = INFINITY;
#pragma unroll 8
    for (int k = 0; k < KNN; ++k) {
      int i = ix[k];
      float h = bse + Pb[(size_t)i * OO + o];
      mx = fmaxf(mx, h);
      mn = fminf(mn, h);
      s1 += h;
      s2 = fmaf(h, h, s2);
    }
    hmax[(size_t)p * OO + o] = mx;
    hmin[(size_t)p * OO + o] = mn;
  }
  __shared__ float red[512];
  red[t] = s1; red[256 + t] = s2;
  __syncthreads();
  if (t < 64) {
    statsP[blk * 128 + t]      = red[t] + red[64 + t] + red[128 + t] + red[192 + t];
    statsP[blk * 128 + 64 + t] = red[256 + t] + red[320 + t] + red[384 + t] + red[448 + t];
  }
}

// ---------------- K4a: parallel partial reduction of statsP ---------------
__global__ __launch_bounds__(256) void k4a_partial(
    const float* __restrict__ statsP, float* __restrict__ part) {
  const int t = threadIdx.x, bi = blockIdx.x;
  const int col = t & 127, rg = t >> 7;  // rg 0/1
  float s = 0.f;
#pragma unroll
  for (int i = 0; i < 4; ++i)
    s += statsP[(bi * 8 + rg * 4 + i) * 128 + col];
  __shared__ float red[256];
  red[t] = s;
  __syncthreads();
  if (t < 128) part[bi * 128 + t] = red[t] + red[128 + t];
}

// ---------------- K4b: finalize BN scale/shift over 128 partials ----------
__global__ __launch_bounds__(256) void k4b_final(
    const float* __restrict__ part, const float* __restrict__ gamma,
    const float* __restrict__ beta, float* __restrict__ scsh) {
  __shared__ float red1[256], red2[256];
  const int t = threadIdx.x;
  const int o = t & 63, c = t >> 6;
  float s1 = 0.f, s2 = 0.f;
  for (int i = c; i < 128; i += 4) {
    s1 += part[i * 128 + o];
    s2 += part[i * 128 + 64 + o];
  }
  red1[t] = s1; red2[t] = s2;
  __syncthreads();
  if (t < 64) {
    s1 = red1[t] + red1[64 + t] + red1[128 + t] + red1[192 + t];
    s2 = red2[t] + red2[64 + t] + red2[128 + t] + red2[192 + t];
    const float inv = 1.0f / 524288.0f;
    float mean = s1 * inv;
    float var = s2 * inv - mean * mean;
    float r = rsqrtf(var + 1e-5f);
    float sc = gamma[t] * r;
    scsh[t] = sc;
    scsh[64 + t] = beta[t] - mean * sc;
  }
}

// ---------------- K5: epilogue: affine+relu on k-max/min, (B,O,N) --------
__global__ __launch_bounds__(256) void k5_epilogue(
    const float* __restrict__ hmax, const float* __restrict__ hmin,
    const float* __restrict__ scsh, float* __restrict__ out) {
  const int id = blockIdx.x * 256 + threadIdx.x;
  const int n = id & 4095, o = (id >> 12) & 63, b = id >> 18;
  float sc = scsh[o], sh = scsh[64 + o];
  size_t hoff = (((size_t)b << 12) + n) * OO + o;
  float H = (sc >= 0.f) ? hmax[hoff] : hmin[hoff];
  float y = sc * H + sh;
  out[id] = y > 0.f ? y : 0.f;
}

extern "C" void kernel_launch(void* const* d_in, const int* in_sizes, int n_in,
                              void* d_out, int out_size, void* d_ws, size_t ws_size,
                              hipStream_t stream) {
  const float* pts   = (const float*)d_in[0];
  const float* W     = (const float*)d_in[1];
  const float* gamma = (const float*)d_in[2];
  const float* beta  = (const float*)d_in[3];
  float* outp = (float*)d_out;
  float* wsf = (float*)d_ws;

  float*          xT    = wsf + XT_OFF;
  float*          sqf   = wsf + SQ_OFF;
  float*          P     = wsf + P_OFF;
  float*          base  = wsf + BASE_OFF;
  float*          hmax  = wsf + HMAX_OFF;
  float*          hmin  = wsf + HMIN_OFF;
  float*          stats = wsf + STATS_OFF;
  float*          scsh  = wsf + SCSH_OFF;
  int*            idx   = (int*)(wsf + IDX_OFF);
  unsigned int*   gapb  = (unsigned int*)(wsf + GAP_OFF);
  int*            i33   = (int*)(wsf + I33_OFF);
  // xh/xl alias hmax/hmin regions (disjoint lifetimes: k1->k2m vs k3->k5)
  unsigned short* xh    = (unsigned short*)(wsf + HMAX_OFF);
  unsigned short* xl    = (unsigned short*)(wsf + HMIN_OFF);
  float*          part  = wsf + P_OFF;   // P region dead after k3

  k1_transpose_sq<<<256, 256, 0, stream>>>(pts, xT, sqf, xh, xl);
  k2b_small_gemm<<<256, 256, 0, stream>>>(xT, W, P, base);

  const int split = (ws_size >= (size_t)(KEYS_OFF + (size_t)NN * NN / 2) * 4u);
  if (split) {
    unsigned short* keys16 = (unsigned short*)(wsf + KEYS_OFF);
    for (int b = 0; b < BB; ++b) {
      k2m_mfma_screen<<<1024, 256, 0, stream>>>(
          xh + (size_t)b * NN * CC, xl + (size_t)b * NN * CC,
          sqf + (size_t)b * NN, keys16);
      k2sel<<<1024, 256, 0, stream>>>(
          keys16, xT + (size_t)b * NN * CC, sqf + (size_t)b * NN,
          idx + (size_t)b * NN * KNN, gapb + (size_t)b * NN,
          i33 + (size_t)b * NN);
    }
  } else {
    k2_gram_select<<<8192, 256, 0, stream>>>(xT, sqf, idx, gapb, i33);
  }
  k2f_flip<<<1, 256, 0, stream>>>(gapb, i33, idx);
  k3_gather_stats<<<1024, 256, 0, stream>>>(P, base, idx, hmax, hmin, stats);
  k4a_partial<<<128, 256, 0, stream>>>(stats, part);
  k4b_final<<<1, 256, 0, stream>>>(part, gamma, beta, scsh);
  k5_epilogue<<<4096, 256, 0, stream>>>(hmax, hmin, scsh, outp);
}

// Round 19
// 416.839 us; speedup vs baseline: 1.1208x; 1.0007x over previous
//
#include <hip/hip_runtime.h>
#include <math.h>

#define BB 4
#define CC 64
#define NN 4096
#define OO 64
#define KNN 32
#define CAND_MAX 192
#define EPS2 0.0625f

// ws layout (float offsets) — base footprint 23.66 MB; split path total
// 57.2 MB (< 90.8 MB R3/R9-proven). xh/xl ALIAS hmax/hmin (disjoint
// lifetimes: xh/xl live k1->k2m; hmax/hmin live k3->k5).
#define XT_OFF    0u          // (B,N,C) fp32          1048576
#define SQ_OFF    1048576u    // (B,N) fp32             16384
#define P_OFF     1064960u    // (B,N,O)               1048576
#define BASE_OFF  2113536u    // (B,N,O)               1048576
#define HMAX_OFF  3162112u    // (B,N,O)               1048576  (k1-k2m: xh)
#define HMIN_OFF  4210688u    // (B,N,O)               1048576  (k1-k2m: xl)
#define STATS_OFF 5259264u    // 1024 x 128            131072
#define SCSH_OFF  5390336u    // 128
#define IDX_OFF   5390464u    // (B,N,K) int32         524288
// gap/i33 overlay the stats region (disjoint lifetimes: k2/k2f before k3)
#define GAP_OFF   5259264u    // (B*N) uint            16384
#define I33_OFF   5275648u    // (B*N) int              16384
// 16-bit screen-key prefixes (split path): one batch (N,N) ushort = 33.5MB
#define KEYS_OFF  5914752u    // (N,N) ushort          8388608 floats

typedef short bf16x8 __attribute__((ext_vector_type(8)));
typedef float f32x4 __attribute__((ext_vector_type(4)));

__device__ __forceinline__ float keyToFloat(unsigned int u) {
  unsigned int b = (u & 0x80000000u) ? (u & 0x7fffffffu) : ~u;
  return __uint_as_float(b);
}
__device__ __forceinline__ unsigned int floatToKey(float f) {
  unsigned int bb = __float_as_uint(f);
  return (bb & 0x80000000u) ? ~bb : (bb | 0x80000000u);
}
__device__ __forceinline__ unsigned short f2bf(float f) {
  unsigned u = __float_as_uint(f);
  unsigned r = ((u >> 16) & 1u) + 0x7fffu;  // RNE
  return (unsigned short)((u + r) >> 16);
}
__device__ __forceinline__ float bf2f(unsigned short h) {
  return __uint_as_float(((unsigned)h) << 16);
}
// load 8 floats at p, split into hi/lo bf16 fragments (fallback path only)
__device__ __forceinline__ void split8(const float* p, bf16x8& h, bf16x8& l) {
  float4 a = *(const float4*)p;
  float4 b = *(const float4*)(p + 4);
  float v[8] = {a.x, a.y, a.z, a.w, b.x, b.y, b.z, b.w};
#pragma unroll
  for (int e = 0; e < 8; ++e) {
    unsigned short hh = f2bf(v[e]);
    h[e] = (short)hh;
    l[e] = (short)f2bf(v[e] - bf2f(hh));
  }
}
// wave-wide sums via ballots — no DS-pipe ops
__device__ __forceinline__ int waveSum7(int local) {
  int s = 0;
#pragma unroll
  for (int b = 0; b < 7; ++b)
    s += (int)__popcll(__ballot((local >> b) & 1)) << b;
  return s;
}
__device__ __forceinline__ int waveSum2(int local) {
  int s = (int)__popcll(__ballot(local & 1));
  s += (int)__popcll(__ballot((local >> 1) & 1)) << 1;
  return s;
}

// ---------------- K1: transpose + sq + precomputed bf16 hi/lo split -------
__global__ __launch_bounds__(256) void k1_transpose_sq(
    const float* __restrict__ pts, float* __restrict__ xT, float* __restrict__ sqf,
    unsigned short* __restrict__ xh, unsigned short* __restrict__ xl) {
  __shared__ float tile[64 * 65];
  __shared__ double sqp[256];
  const int t = threadIdx.x, blk = blockIdx.x;
  const int b = blk >> 6, n0 = (blk & 63) << 6;
  const float* pb = pts + (size_t)b * CC * NN;
  const int j = t & 63, cg = t >> 6;
  double acc = 0.0;
#pragma unroll
  for (int i = 0; i < 16; ++i) {
    int c = cg * 16 + i;
    float v = pb[(size_t)c * NN + n0 + j];
    tile[c * 65 + j] = v;
    acc += (double)v * (double)v;
  }
  sqp[t] = acc;
  __syncthreads();
  const int c2 = t & 63, jg = t >> 6;
#pragma unroll
  for (int i = 0; i < 16; ++i) {
    int jj = jg * 16 + i;
    float vv = tile[c2 * 65 + jj];
    size_t xoff = ((size_t)b * NN + n0 + jj) * CC + c2;
    xT[xoff] = vv;
    unsigned short hh = f2bf(vv);
    xh[xoff] = hh;
    xl[xoff] = f2bf(vv - bf2f(hh));
  }
  if (t < 64)
    sqf[b * NN + n0 + t] = (float)(sqp[t] + sqp[64 + t] + sqp[128 + t] + sqp[192 + t]);
}

// ---------------- K2b: P = x.w2^T, base = x.(w1-w2)^T ---------------------
__global__ __launch_bounds__(256) void k2b_small_gemm(
    const float* __restrict__ xT, const float* __restrict__ W,
    float* __restrict__ P, float* __restrict__ base) {
  __shared__ float w2T[64 * 65];
  __shared__ float wdT[64 * 65];
  __shared__ float xbuf[4 * 64];
  const int t = threadIdx.x, blk = blockIdx.x;
  const int b = blk >> 6, n0 = (blk & 63) << 6;
#pragma unroll
  for (int i = 0; i < 16; ++i) {
    int e = i * 256 + t, o = e >> 6, c = e & 63;
    w2T[c * 65 + o] = W[o * 128 + 64 + c];
  }
  __syncthreads();
#pragma unroll
  for (int i = 0; i < 16; ++i) {
    int e = i * 256 + t, o = e >> 6, c = e & 63;
    wdT[c * 65 + o] = W[o * 128 + c] - w2T[c * 65 + o];
  }
  __syncthreads();
  const int w = t >> 6, lane = t & 63;
  for (int it = 0; it < 16; ++it) {
    int n = n0 + it * 4 + w;
    xbuf[t] = xT[((size_t)b * NN + n) * CC + lane];
    __syncthreads();
    float accP = 0.f, accB = 0.f;
#pragma unroll
    for (int c = 0; c < 64; ++c) {
      float xc = xbuf[w * 64 + c];
      accP = fmaf(xc, w2T[c * 65 + lane], accP);
      accB = fmaf(xc, wdT[c * 65 + lane], accB);
    }
    size_t off = ((size_t)b * NN + n) * OO + lane;
    P[off] = accP;
    base[off] = accB;
    __syncthreads();
  }
}

// ---------------- K2m: MFMA screen -> LDS-staged coalesced key writes -----
// CHANGE vs R18: keys written via LDS staging. The direct store pattern
// (2B at [(rowb+v)*NN+colg]) made 32-byte transactions (4x write
// amplification on 33.5MB/batch). Now: stage the block's 32x512 ushort key
// tile in LDS (32KB), then block-cooperative write-out where each 64-lane
// group stores one row's 1KB contiguously (uint4). Screen math identical.
__global__ __launch_bounds__(256) void k2m_mfma_screen(
    const unsigned short* __restrict__ xhb, const unsigned short* __restrict__ xlb,
    const float* __restrict__ sqb, unsigned short* __restrict__ keys16) {
  __shared__ unsigned short ktile[32 * 512];  // 32KB
  const int t = threadIdx.x, blk = blockIdx.x;
  const int stripe = blk >> 3;   // rows stripe*32..+31
  const int chunk = blk & 7;     // cols chunk*512..+511
  const int wid = t >> 6, l = t & 63;
  const int r0 = stripe * 32;
  const int cbase = chunk * 512 + wid * 128;
  const int i16 = l & 15, kb = l >> 4;

  bf16x8 ah[2][2], al[2][2];
#pragma unroll
  for (int rt = 0; rt < 2; ++rt) {
    size_t rb = (size_t)(r0 + rt * 16 + i16) * CC + kb * 8;
#pragma unroll
    for (int kc = 0; kc < 2; ++kc) {
      ah[rt][kc] = *(const bf16x8*)&xhb[rb + kc * 32];
      al[rt][kc] = *(const bf16x8*)&xlb[rb + kc * 32];
    }
  }
  float srow[2][4];
#pragma unroll
  for (int rt = 0; rt < 2; ++rt)
#pragma unroll
    for (int v = 0; v < 4; ++v)
      srow[rt][v] = sqb[r0 + rt * 16 + kb * 4 + v];

  for (int ct = 0; ct < 8; ++ct) {
    const int colg = cbase + ct * 16 + i16;
    bf16x8 bh[2], bl[2];
    size_t cb = (size_t)colg * CC + kb * 8;
#pragma unroll
    for (int kc = 0; kc < 2; ++kc) {
      bh[kc] = *(const bf16x8*)&xhb[cb + kc * 32];
      bl[kc] = *(const bf16x8*)&xlb[cb + kc * 32];
    }
    const float sqc = sqb[colg];
    const int lcol = wid * 128 + ct * 16 + i16;
#pragma unroll
    for (int rt = 0; rt < 2; ++rt) {
      f32x4 acc = {0.f, 0.f, 0.f, 0.f};
#pragma unroll
      for (int kc = 0; kc < 2; ++kc) {
        acc = __builtin_amdgcn_mfma_f32_16x16x32_bf16(ah[rt][kc], bh[kc], acc, 0, 0, 0);
        acc = __builtin_amdgcn_mfma_f32_16x16x32_bf16(ah[rt][kc], bl[kc], acc, 0, 0, 0);
        acc = __builtin_amdgcn_mfma_f32_16x16x32_bf16(al[rt][kc], bh[kc], acc, 0, 0, 0);
      }
      const int lrow = rt * 16 + kb * 4;
#pragma unroll
      for (int v = 0; v < 4; ++v) {
        float d = 2.0f * acc[v] - srow[rt][v] - sqc;
        ktile[(lrow + v) * 512 + lcol] = (unsigned short)(floatToKey(d) >> 16);
      }
    }
  }
  __syncthreads();
  // coalesced write-out: 2048 uint4; group of 64 lanes stores one row (1KB)
  uint4* kout = (uint4*)keys16;
#pragma unroll
  for (int i = 0; i < 8; ++i) {
    int e = i * 256 + t;
    int r = e >> 6, c4 = e & 63;
    kout[(size_t)(r0 + r) * (NN / 8) + chunk * 64 + c4] =
        ((const uint4*)ktile)[r * 64 + c4];
  }
}

// ---------------- K2sel: per-wave select on 16-bit prefixes (R18-verified)
__global__ __launch_bounds__(256) void k2sel(
    const unsigned short* __restrict__ keysb, const float* __restrict__ xbp,
    const float* __restrict__ sqb, int* __restrict__ idxout,
    unsigned int* __restrict__ gapb, int* __restrict__ i33out) {
  __shared__ int cnd_gi[4][CAND_MAX];
  __shared__ int cnd_cnt[4];
  __shared__ int sh_list[4][32];
  __shared__ int sh_eq[4][96];
  __shared__ unsigned int sh_kmin[4];
  __shared__ int sh_ngt[4], sh_i33[4], sh_mx[4], sh_cnt[4], sh_ecnt[4];

  const int t = threadIdx.x, blk = blockIdx.x;
  const int v = t >> 6, l = t & 63;
  const int p = blk * 4 + v;  // this wave's row
  const float srf = sqb[p];

  // 64 key-prefixes/thread: uint4 q covers ushorts gi = q*512 + l*8 .. +7
  uint4 kq[8];
  {
    const uint4* kp = (const uint4*)(keysb + (size_t)p * NN);
#pragma unroll
    for (int q = 0; q < 8; ++q) kq[q] = kp[q * 64 + l];
  }
  if (l == 0) {
    cnd_cnt[v] = 0;
    sh_ngt[v] = 0; sh_kmin[v] = 0xffffffffu; sh_i33[v] = 0x7fffffff;
    sh_mx[v] = -1; sh_cnt[v] = 0; sh_ecnt[v] = 0;
  }
  __syncthreads();

  // ---- phase 2: binary search on 16-bit prefixes (ballot-counted) --------
  unsigned int Pv = 0;
  int R = 33;
  for (int bit = 15; bit >= 0; --bit) {
    unsigned int tgt = (Pv >> bit) | 1u;
    int local = 0;
#pragma unroll
    for (int q = 0; q < 8; ++q) {
      uint4 kv = kq[q];
      unsigned int us[4] = {kv.x, kv.y, kv.z, kv.w};
#pragma unroll
      for (int j = 0; j < 4; ++j) {
        unsigned int lo = us[j] & 0xffffu, hi = us[j] >> 16;
        local += ((lo >> bit) == tgt) + ((hi >> bit) == tgt);
      }
    }
    int c1 = waveSum7(local);
    if (c1 >= R) Pv |= (1u << bit); else R -= c1;
  }
  const float v33q = keyToFloat(Pv << 16);   // <= s(33) in float order
  const unsigned int thr16 = floatToKey(v33q - EPS2) >> 16;

  // ---- phase 3: collect candidates (prefix >= thr16) ---------------------
#pragma unroll
  for (int q = 0; q < 8; ++q) {
    uint4 kv = kq[q];
    unsigned int us[4] = {kv.x, kv.y, kv.z, kv.w};
#pragma unroll
    for (int j = 0; j < 4; ++j) {
      unsigned int lo = us[j] & 0xffffu, hi = us[j] >> 16;
      int gib = q * 512 + l * 8 + 2 * j;
      if (lo >= thr16) {
        int pos = atomicAdd(&cnd_cnt[v], 1);
        if (pos < CAND_MAX) cnd_gi[v][pos] = gib;
      }
      if (hi >= thr16) {
        int pos = atomicAdd(&cnd_cnt[v], 1);
        if (pos < CAND_MAX) cnd_gi[v][pos] = gib + 1;
      }
    }
  }
  __syncthreads();
  const int M = cnd_cnt[v] < CAND_MAX ? cnd_cnt[v] : CAND_MAX;

  // ---- phase 4: exact fp64-round-once keys (<=3 candidates/lane) ---------
  unsigned int ek[3] = {0u, 0u, 0u};
  int eg[3] = {-1, -1, -1};
  {
    const float4* rp = (const float4*)(xbp + (size_t)p * CC);
#pragma unroll
    for (int c3 = 0; c3 < 3; ++c3) {
      int ci = l + 64 * c3;
      if (ci < M) {
        int gi = cnd_gi[v][ci];
        const float4* mp = (const float4*)&xbp[(size_t)gi * CC];
        double acc = 0.0;
#pragma unroll
        for (int cq = 0; cq < 16; ++cq) {
          float4 rv = rp[cq];
          float4 mv = mp[cq];
          acc += (double)rv.x * (double)mv.x + (double)rv.y * (double)mv.y +
                 (double)rv.z * (double)mv.z + (double)rv.w * (double)mv.w;
        }
        float g = (float)acc;    // fp64 dot rounded once to fp32
        float d = 2.0f * g - srf;
        d = d - sqb[gi];
        ek[c3] = floatToKey(d);
        eg[c3] = gi;
      }
      asm volatile("" ::: "memory");  // no cross-candidate load hoisting
    }
  }

  // ---- phase 5: exact K33 binary search over candidates (ballot) ---------
  unsigned int Pe = 0;
  R = 33;
  for (int bit = 31; bit >= 0; --bit) {
    unsigned int tgt = (Pe >> bit) | 1u;
    int local = 0;
#pragma unroll
    for (int c3 = 0; c3 < 3; ++c3)
      local += (eg[c3] >= 0) && ((ek[c3] >> bit) == tgt);
    int c1 = waveSum2(local);
    if (c1 >= R) Pe |= (1u << bit); else R -= c1;
  }
  const unsigned int K33 = Pe;

  int ngt_loc = 0;
  unsigned int kmin_loc = 0xffffffffu;
#pragma unroll
  for (int c3 = 0; c3 < 3; ++c3) {
    if (eg[c3] >= 0) {
      if (ek[c3] > K33) { ngt_loc++; kmin_loc = ek[c3] < kmin_loc ? ek[c3] : kmin_loc; }
      if (ek[c3] == K33) atomicMin(&sh_i33[v], eg[c3]);
    }
  }
  if (ngt_loc) { atomicAdd(&sh_ngt[v], ngt_loc); atomicMin(&sh_kmin[v], kmin_loc); }
  __syncthreads();

  const int ngt = sh_ngt[v];
  const unsigned int K32 = (ngt == 32) ? sh_kmin[v] : K33;
#pragma unroll
  for (int c3 = 0; c3 < 3; ++c3) {
    if (eg[c3] >= 0) {
      if (ek[c3] > K33) { int pos = atomicAdd(&sh_cnt[v], 1); sh_list[v][pos] = eg[c3]; }
      if (ngt == 32 && ek[c3] == K32) atomicMax(&sh_mx[v], eg[c3]);
      if (ngt < 32 && ek[c3] == K33) { int pos = atomicAdd(&sh_ecnt[v], 1); if (pos < 96) sh_eq[v][pos] = eg[c3]; }
    }
  }
  __syncthreads();

  if (l == 0) {
    if (ngt == 32) {
      int target = sh_mx[v], pos = 31;
      for (int q2 = 0; q2 < 32; ++q2) if (sh_list[v][q2] == target) pos = q2;
      int tmp = sh_list[v][31]; sh_list[v][31] = sh_list[v][pos]; sh_list[v][pos] = tmp;
      gapb[p] = __float_as_uint(__fsub_rn(keyToFloat(K32), keyToFloat(K33)));
      i33out[p] = sh_i33[v];
    } else {
      int ec = sh_ecnt[v]; if (ec > 96) ec = 96;
      for (int a = 1; a < ec; ++a) {
        int vv = sh_eq[v][a]; int bp = a - 1;
        while (bp >= 0 && sh_eq[v][bp] > vv) { sh_eq[v][bp + 1] = sh_eq[v][bp]; --bp; }
        sh_eq[v][bp + 1] = vv;
      }
      int need = 32 - ngt;
      for (int a = 0; a < need; ++a) sh_list[v][ngt + a] = sh_eq[v][a];
      gapb[p] = 0x7f800000u;
      i33out[p] = (need < ec) ? sh_eq[v][need] : -1;
    }
  }
  __syncthreads();
  if (l < 32) idxout[(size_t)p * KNN + l] = sh_list[v][l];
}

// ---------------- K2 (fallback, R8-verified): fused screen+select ---------
__global__ __launch_bounds__(256, 2) void k2_gram_select(
    const float* __restrict__ xT, const float* __restrict__ sqf,
    int* __restrict__ idxout, unsigned int* __restrict__ gapb,
    int* __restrict__ i33out) {
  __shared__ __align__(16) float xmT2[2][8192];
  __shared__ float sqm2[2][128];
  __shared__ float xchb[2][256];
  __shared__ int rowcnt[2][4];
  __shared__ int cnd_gi[2][CAND_MAX];
  __shared__ int cnd_cnt[2];
  __shared__ int sh_list[2][32];
  __shared__ int sh_eq[2][96];
  __shared__ unsigned int sh_kmin[2];
  __shared__ int sh_ngt[2], sh_i33[2], sh_mx[2], sh_cnt[2], sh_ecnt[2];

  const int t = threadIdx.x, blk = blockIdx.x;
  const int p0 = blk * 2;
  const int b = p0 >> 12;
  const int row = t >> 7;
  const int col = t & 127;
  const int wid = t >> 6;
  const int sXor = col & 7;
  const float* xbp = xT + (size_t)b * NN * CC;
  const float* sqb = sqf + (size_t)b * NN;

  float4 xa[8], xb4[8];
  {
    const float4* r0 = (const float4*)(xT + (size_t)p0 * CC);
    const float4* r1 = (const float4*)(xT + (size_t)(p0 + 1) * CC);
#pragma unroll
    for (int j = 0; j < 8; ++j) { xa[j] = r0[8 * row + j]; xb4[j] = r1[8 * row + j]; }
  }
  const float srf = sqf[p0 + row];

  unsigned int keys32[32];

  auto stage = [&](int tt, float* xmb, float* sqmb) {
    const int m0s = tt << 7;
#pragma unroll
    for (int q = 0; q < 8; ++q) {
      int e = q * 256 + t;
      int c2 = e >> 4, slot = e & 15;
      const float4* gsrc = (const float4*)xbp + (((size_t)(m0s + c2)) << 4) + (slot ^ (c2 & 7));
      __builtin_amdgcn_global_load_lds(
          (const __attribute__((address_space(1))) void*)gsrc,
          (__attribute__((address_space(3))) void*)(xmb + (size_t)e * 4), 16, 0, 0);
    }
    if (t < 128)
      __builtin_amdgcn_global_load_lds(
          (const __attribute__((address_space(1))) void*)(sqb + m0s + t),
          (__attribute__((address_space(3))) void*)(sqmb + t), 4, 0, 0);
  };

  stage(0, xmT2[0], sqm2[0]);
  float pendA = 0.f, pendB = 0.f, pendSq = 0.f;
#pragma unroll
  for (int tile = 0; tile < 32; ++tile) {
    const int curb = tile & 1;
    asm volatile("s_waitcnt vmcnt(0)" ::: "memory");
    __syncthreads();
    if (tile > 0) {
      float other = xchb[(tile - 1) & 1][t ^ 128];
      float acc = (row == 0) ? (pendA + other) : (other + pendB);
      float dd = 2.0f * acc - srf;
      dd = dd - pendSq;
      keys32[tile - 1] = floatToKey(dd);
    }
    if (tile < 31) stage(tile + 1, xmT2[curb ^ 1], sqm2[curb ^ 1]);
    const float* xm = xmT2[curb];
    float pA = 0.f, pB = 0.f;
#pragma unroll
    for (int j = 0; j < 8; ++j) {
      int slot = (8 * row + j) ^ sXor;
      float4 mv = *(const float4*)&xm[col * 64 + slot * 4];
      pA = fmaf(xa[j].x, mv.x, pA); pA = fmaf(xa[j].y, mv.y, pA);
      pA = fmaf(xa[j].z, mv.z, pA); pA = fmaf(xa[j].w, mv.w, pA);
      pB = fmaf(xb4[j].x, mv.x, pB); pB = fmaf(xb4[j].y, mv.y, pB);
      pB = fmaf(xb4[j].z, mv.z, pB); pB = fmaf(xb4[j].w, mv.w, pB);
    }
    pendA = pA; pendB = pB; pendSq = sqm2[curb][col];
    xchb[tile & 1][t] = (row == 0) ? pB : pA;
  }
  __syncthreads();
  {
    float other = xchb[1][t ^ 128];
    float acc = (row == 0) ? (pendA + other) : (other + pendB);
    float dd = 2.0f * acc - srf;
    dd = dd - pendSq;
    keys32[31] = floatToKey(dd);
  }
  __syncthreads();
  if ((t & 127) == 0) cnd_cnt[row] = 0;

  unsigned int Pv = 0;
  int R = 33;
  for (int bit = 31; bit >= 0; --bit) {
    unsigned int tgt = (Pv >> bit) | 1u;
    int local = 0;
#pragma unroll
    for (int i = 0; i < 32; ++i) local += ((keys32[i] >> bit) == tgt) ? 1 : 0;
#pragma unroll
    for (int off = 32; off > 0; off >>= 1) local += __shfl_down(local, off, 64);
    if ((t & 63) == 0) rowcnt[bit & 1][wid] = local;
    __syncthreads();
    int c1 = rowcnt[bit & 1][row * 2] + rowcnt[bit & 1][row * 2 + 1];
    if (c1 >= R) Pv |= (1u << bit); else R -= c1;
  }
  const unsigned int thr = floatToKey(keyToFloat(Pv) - EPS2);

#pragma unroll
  for (int i = 0; i < 32; ++i) {
    if (keys32[i] >= thr) {
      int pos = atomicAdd(&cnd_cnt[row], 1);
      if (pos < CAND_MAX) cnd_gi[row][pos] = (i << 7) + col;
    }
  }
  __syncthreads();
  const int M = cnd_cnt[row] < CAND_MAX ? cnd_cnt[row] : CAND_MAX;

  {
    const float4* xrp = (const float4*)(xT + (size_t)(p0 + row) * CC);
#pragma unroll
    for (int j = 0; j < 8; ++j) { xa[j] = xrp[j]; xb4[j] = xrp[8 + j]; }
  }
  unsigned int ek0 = 0u, ek1 = 0u;
  int eg0 = -1, eg1 = -1;
  if (col < M) {
    int gi = cnd_gi[row][col];
    const float4* mp = (const float4*)&xbp[(size_t)gi * CC];
    double acc = 0.0;
#pragma unroll
    for (int cq = 0; cq < 8; ++cq) {
      float4 mv = mp[cq];
      acc += (double)xa[cq].x * (double)mv.x + (double)xa[cq].y * (double)mv.y +
             (double)xa[cq].z * (double)mv.z + (double)xa[cq].w * (double)mv.w;
    }
#pragma unroll
    for (int cq = 0; cq < 8; ++cq) {
      float4 mv = mp[8 + cq];
      acc += (double)xb4[cq].x * (double)mv.x + (double)xb4[cq].y * (double)mv.y +
             (double)xb4[cq].z * (double)mv.z + (double)xb4[cq].w * (double)mv.w;
    }
    float g = (float)acc;
    float d = 2.0f * g - srf;
    d = d - sqb[gi];
    ek0 = floatToKey(d);
    eg0 = gi;
  }
  if (col + 128 < M) {
    int gi = cnd_gi[row][col + 128];
    const float4* mp = (const float4*)&xbp[(size_t)gi * CC];
    double acc = 0.0;
#pragma unroll
    for (int cq = 0; cq < 8; ++cq) {
      float4 mv = mp[cq];
      acc += (double)xa[cq].x * (double)mv.x + (double)xa[cq].y * (double)mv.y +
             (double)xa[cq].z * (double)mv.z + (double)xa[cq].w * (double)mv.w;
    }
#pragma unroll
    for (int cq = 0; cq < 8; ++cq) {
      float4 mv = mp[8 + cq];
      acc += (double)xb4[cq].x * (double)mv.x + (double)xb4[cq].y * (double)mv.y +
             (double)xb4[cq].z * (double)mv.z + (double)xb4[cq].w * (double)mv.w;
    }
    float g = (float)acc;
    float d = 2.0f * g - srf;
    d = d - sqb[gi];
    ek1 = floatToKey(d);
    eg1 = gi;
  }

  Pv = 0;
  R = 33;
  for (int bit = 31; bit >= 0; --bit) {
    unsigned int tgt = (Pv >> bit) | 1u;
    int local = ((eg0 >= 0) && ((ek0 >> bit) == tgt)) +
                ((eg1 >= 0) && ((ek1 >> bit) == tgt));
#pragma unroll
    for (int off = 32; off > 0; off >>= 1) local += __shfl_down(local, off, 64);
    if ((t & 63) == 0) rowcnt[bit & 1][wid] = local;
    __syncthreads();
    int c1 = rowcnt[bit & 1][row * 2] + rowcnt[bit & 1][row * 2 + 1];
    if (c1 >= R) Pv |= (1u << bit); else R -= c1;
  }
  const unsigned int K33 = Pv;

  if ((t & 127) == 0) {
    sh_ngt[row] = 0; sh_kmin[row] = 0xffffffffu; sh_i33[row] = 0x7fffffff;
    sh_mx[row] = -1; sh_cnt[row] = 0; sh_ecnt[row] = 0;
  }
  __syncthreads();

  int ngt_loc = 0;
  unsigned int kmin_loc = 0xffffffffu;
  if (eg0 >= 0) {
    if (ek0 > K33) { ngt_loc++; kmin_loc = ek0 < kmin_loc ? ek0 : kmin_loc; }
    if (ek0 == K33) atomicMin(&sh_i33[row], eg0);
  }
  if (eg1 >= 0) {
    if (ek1 > K33) { ngt_loc++; kmin_loc = ek1 < kmin_loc ? ek1 : kmin_loc; }
    if (ek1 == K33) atomicMin(&sh_i33[row], eg1);
  }
  if (ngt_loc) { atomicAdd(&sh_ngt[row], ngt_loc); atomicMin(&sh_kmin[row], kmin_loc); }
  __syncthreads();

  const int ngt = sh_ngt[row];
  const unsigned int K32 = (ngt == 32) ? sh_kmin[row] : K33;
  if (eg0 >= 0) {
    if (ek0 > K33) { int pos = atomicAdd(&sh_cnt[row], 1); sh_list[row][pos] = eg0; }
    if (ngt == 32 && ek0 == K32) atomicMax(&sh_mx[row], eg0);
    if (ngt < 32 && ek0 == K33) { int pos = atomicAdd(&sh_ecnt[row], 1); if (pos < 96) sh_eq[row][pos] = eg0; }
  }
  if (eg1 >= 0) {
    if (ek1 > K33) { int pos = atomicAdd(&sh_cnt[row], 1); sh_list[row][pos] = eg1; }
    if (ngt == 32 && ek1 == K32) atomicMax(&sh_mx[row], eg1);
    if (ngt < 32 && ek1 == K33) { int pos = atomicAdd(&sh_ecnt[row], 1); if (pos < 96) sh_eq[row][pos] = eg1; }
  }
  __syncthreads();

  if ((t & 127) == 0) {
    const int p = p0 + row;
    if (ngt == 32) {
      int target = sh_mx[row], pos = 31;
      for (int q2 = 0; q2 < 32; ++q2) if (sh_list[row][q2] == target) pos = q2;
      int tmp = sh_list[row][31]; sh_list[row][31] = sh_list[row][pos]; sh_list[row][pos] = tmp;
      gapb[p] = __float_as_uint(__fsub_rn(keyToFloat(K32), keyToFloat(K33)));
      i33out[p] = sh_i33[row];
    } else {
      int ec = sh_ecnt[row]; if (ec > 96) ec = 96;
      for (int a = 1; a < ec; ++a) {
        int v = sh_eq[row][a]; int bp = a - 1;
        while (bp >= 0 && sh_eq[row][bp] > v) { sh_eq[row][bp + 1] = sh_eq[row][bp]; --bp; }
        sh_eq[row][bp + 1] = v;
      }
      int need = 32 - ngt;
      for (int a = 0; a < need; ++a) sh_list[row][ngt + a] = sh_eq[row][a];
      gapb[p] = 0x7f800000u;
      i33out[p] = (need < ec) ? sh_eq[row][need] : -1;
    }
  }
  __syncthreads();
  if (t < 64) {
    int rr = t >> 5, k = t & 31;
    idxout[(size_t)(p0 + rr) * KNN + k] = sh_list[rr][k];
  }
}

// ---------------- K2f: flip the globally smallest-positive-gap row --------
__global__ __launch_bounds__(256) void k2f_flip(
    const unsigned int* __restrict__ gapb, const int* __restrict__ i33,
    int* __restrict__ idxout) {
  __shared__ unsigned int sk[256];
  __shared__ int sv[256];
  const int t = threadIdx.x;
  unsigned int best = 0xffffffffu;
  int brow = -1;
  for (int i = t; i < BB * NN; i += 256) {
    unsigned int g = gapb[i];
    if (g < best) { best = g; brow = i; }
  }
  sk[t] = best; sv[t] = brow;
  __syncthreads();
  for (int s = 128; s > 0; s >>= 1) {
    if (t < s && sk[t + s] < sk[t]) { sk[t] = sk[t + s]; sv[t] = sv[t + s]; }
    __syncthreads();
  }
  if (t == 0 && sv[0] >= 0 && sk[0] > 0u && sk[0] < 0x7f800000u) {
    idxout[(size_t)sv[0] * KNN + 31] = i33[sv[0]];
  }
}

// ---------------- K3: gather h=base+P[idx], k-max/min + BN partials -------
__global__ __launch_bounds__(256) void k3_gather_stats(
    const float* __restrict__ Pm, const float* __restrict__ basem,
    const int* __restrict__ idxb, float* __restrict__ hmax,
    float* __restrict__ hmin, float* __restrict__ statsP) {
  const int t = threadIdx.x, blk = blockIdx.x;
  const int w = t >> 6, o = t & 63;
  float s1 = 0.f, s2 = 0.f;
#pragma unroll
  for (int q = 0; q < 4; ++q) {
    int p = blk * 16 + w * 4 + q;
    int b = p >> 12;
    const float* Pb = Pm + (size_t)b * NN * OO;
    float bse = basem[(size_t)p * OO + o];
    const int* ix = idxb + (size_t)p * KNN;
    float mx = -INFINITY, mn = INFINITY;
#pragma unroll 8
    for (int k = 0; k < KNN; ++k) {
      int i = ix[k];
      float h = bse + Pb[(size_t)i * OO + o];
      mx = fmaxf(mx, h);
      mn = fminf(mn, h);
      s1 += h;
      s2 = fmaf(h, h, s2);
    }
    hmax[(size_t)p * OO + o] = mx;
    hmin[(size_t)p * OO + o] = mn;
  }
  __shared__ float red[512];
  red[t] = s1; red[256 + t] = s2;
  __syncthreads();
  if (t < 64) {
    statsP[blk * 128 + t]      = red[t] + red[64 + t] + red[128 + t] + red[192 + t];
    statsP[blk * 128 + 64 + t] = red[256 + t] + red[320 + t] + red[384 + t] + red[448 + t];
  }
}

// ---------------- K4a: parallel partial reduction of statsP ---------------
__global__ __launch_bounds__(256) void k4a_partial(
    const float* __restrict__ statsP, float* __restrict__ part) {
  const int t = threadIdx.x, bi = blockIdx.x;
  const int col = t & 127, rg = t >> 7;  // rg 0/1
  float s = 0.f;
#pragma unroll
  for (int i = 0; i < 4; ++i)
    s += statsP[(bi * 8 + rg * 4 + i) * 128 + col];
  __shared__ float red[256];
  red[t] = s;
  __syncthreads();
  if (t < 128) part[bi * 128 + t] = red[t] + red[128 + t];
}

// ---------------- K4b: finalize BN scale/shift over 128 partials ----------
__global__ __launch_bounds__(256) void k4b_final(
    const float* __restrict__ part, const float* __restrict__ gamma,
    const float* __restrict__ beta, float* __restrict__ scsh) {
  __shared__ float red1[256], red2[256];
  const int t = threadIdx.x;
  const int o = t & 63, c = t >> 6;
  float s1 = 0.f, s2 = 0.f;
  for (int i = c; i < 128; i += 4) {
    s1 += part[i * 128 + o];
    s2 += part[i * 128 + 64 + o];
  }
  red1[t] = s1; red2[t] = s2;
  __syncthreads();
  if (t < 64) {
    s1 = red1[t] + red1[64 + t] + red1[128 + t] + red1[192 + t];
    s2 = red2[t] + red2[64 + t] + red2[128 + t] + red2[192 + t];
    const float inv = 1.0f / 524288.0f;
    float mean = s1 * inv;
    float var = s2 * inv - mean * mean;
    float r = rsqrtf(var + 1e-5f);
    float sc = gamma[t] * r;
    scsh[t] = sc;
    scsh[64 + t] = beta[t] - mean * sc;
  }
}

// ---------------- K5: epilogue: affine+relu on k-max/min, (B,O,N) --------
__global__ __launch_bounds__(256) void k5_epilogue(
    const float* __restrict__ hmax, const float* __restrict__ hmin,
    const float* __restrict__ scsh, float* __restrict__ out) {
  const int id = blockIdx.x * 256 + threadIdx.x;
  const int n = id & 4095, o = (id >> 12) & 63, b = id >> 18;
  float sc = scsh[o], sh = scsh[64 + o];
  size_t hoff = (((size_t)b << 12) + n) * OO + o;
  float H = (sc >= 0.f) ? hmax[hoff] : hmin[hoff];
  float y = sc * H + sh;
  out[id] = y > 0.f ? y : 0.f;
}

extern "C" void kernel_launch(void* const* d_in, const int* in_sizes, int n_in,
                              void* d_out, int out_size, void* d_ws, size_t ws_size,
                              hipStream_t stream) {
  const float* pts   = (const float*)d_in[0];
  const float* W     = (const float*)d_in[1];
  const float* gamma = (const float*)d_in[2];
  const float* beta  = (const float*)d_in[3];
  float* outp = (float*)d_out;
  float* wsf = (float*)d_ws;

  float*          xT    = wsf + XT_OFF;
  float*          sqf   = wsf + SQ_OFF;
  float*          P     = wsf + P_OFF;
  float*          base  = wsf + BASE_OFF;
  float*          hmax  = wsf + HMAX_OFF;
  float*          hmin  = wsf + HMIN_OFF;
  float*          stats = wsf + STATS_OFF;
  float*          scsh  = wsf + SCSH_OFF;
  int*            idx   = (int*)(wsf + IDX_OFF);
  unsigned int*   gapb  = (unsigned int*)(wsf + GAP_OFF);
  int*            i33   = (int*)(wsf + I33_OFF);
  // xh/xl alias hmax/hmin regions (disjoint lifetimes: k1->k2m vs k3->k5)
  unsigned short* xh    = (unsigned short*)(wsf + HMAX_OFF);
  unsigned short* xl    = (unsigned short*)(wsf + HMIN_OFF);
  float*          part  = wsf + P_OFF;   // P region dead after k3

  k1_transpose_sq<<<256, 256, 0, stream>>>(pts, xT, sqf, xh, xl);
  k2b_small_gemm<<<256, 256, 0, stream>>>(xT, W, P, base);

  const int split = (ws_size >= (size_t)(KEYS_OFF + (size_t)NN * NN / 2) * 4u);
  if (split) {
    unsigned short* keys16 = (unsigned short*)(wsf + KEYS_OFF);
    for (int b = 0; b < BB; ++b) {
      k2m_mfma_screen<<<1024, 256, 0, stream>>>(
          xh + (size_t)b * NN * CC, xl + (size_t)b * NN * CC,
          sqf + (size_t)b * NN, keys16);
      k2sel<<<1024, 256, 0, stream>>>(
          keys16, xT + (size_t)b * NN * CC, sqf + (size_t)b * NN,
          idx + (size_t)b * NN * KNN, gapb + (size_t)b * NN,
          i33 + (size_t)b * NN);
    }
  } else {
    k2_gram_select<<<8192, 256, 0, stream>>>(xT, sqf, idx, gapb, i33);
  }
  k2f_flip<<<1, 256, 0, stream>>>(gapb, i33, idx);
  k3_gather_stats<<<1024, 256, 0, stream>>>(P, base, idx, hmax, hmin, stats);
  k4a_partial<<<128, 256, 0, stream>>>(stats, part);
  k4b_final<<<1, 256, 0, stream>>>(part, gamma, beta, scsh);
  k5_epilogue<<<4096, 256, 0, stream>>>(hmax, hmin, scsh, outp);
}

// Round 20
// 376.924 us; speedup vs baseline: 1.2395x; 1.1059x over previous
//
#include <hip/hip_runtime.h>
#include <math.h>

#define BB 4
#define CC 64
#define NN 4096
#define OO 64
#define KNN 32
#define CAND_MAX 192
#define EPS2 0.0625f

// ws layout (float offsets) — base footprint 23.66 MB; split path total
// 57.2 MB (< 90.8 MB R3/R9-proven). xh/xl ALIAS hmax/hmin (disjoint
// lifetimes: xh/xl live k1->k2m; hmax/hmin live k3->k5).
#define XT_OFF    0u          // (B,N,C) fp32          1048576
#define SQ_OFF    1048576u    // (B,N) fp32             16384
#define P_OFF     1064960u    // (B,N,O)               1048576
#define BASE_OFF  2113536u    // (B,N,O)               1048576
#define HMAX_OFF  3162112u    // (B,N,O)               1048576  (k1-k2m: xh)
#define HMIN_OFF  4210688u    // (B,N,O)               1048576  (k1-k2m: xl)
#define STATS_OFF 5259264u    // 1024 x 128            131072
#define SCSH_OFF  5390336u    // 128
#define IDX_OFF   5390464u    // (B,N,K) int32         524288
// gap/i33 overlay the stats region (disjoint lifetimes: k2/k2f before k3)
#define GAP_OFF   5259264u    // (B*N) uint            16384
#define I33_OFF   5275648u    // (B*N) int              16384
// 16-bit screen-key prefixes (split path): one batch (N,N) ushort = 33.5MB
#define KEYS_OFF  5914752u    // (N,N) ushort          8388608 floats

typedef short bf16x8 __attribute__((ext_vector_type(8)));
typedef float f32x4 __attribute__((ext_vector_type(4)));

__device__ __forceinline__ float keyToFloat(unsigned int u) {
  unsigned int b = (u & 0x80000000u) ? (u & 0x7fffffffu) : ~u;
  return __uint_as_float(b);
}
__device__ __forceinline__ unsigned int floatToKey(float f) {
  unsigned int bb = __float_as_uint(f);
  return (bb & 0x80000000u) ? ~bb : (bb | 0x80000000u);
}
__device__ __forceinline__ unsigned short f2bf(float f) {
  unsigned u = __float_as_uint(f);
  unsigned r = ((u >> 16) & 1u) + 0x7fffu;  // RNE
  return (unsigned short)((u + r) >> 16);
}
__device__ __forceinline__ float bf2f(unsigned short h) {
  return __uint_as_float(((unsigned)h) << 16);
}
// load 8 floats at p, split into hi/lo bf16 fragments (fallback path only)
__device__ __forceinline__ void split8(const float* p, bf16x8& h, bf16x8& l) {
  float4 a = *(const float4*)p;
  float4 b = *(const float4*)(p + 4);
  float v[8] = {a.x, a.y, a.z, a.w, b.x, b.y, b.z, b.w};
#pragma unroll
  for (int e = 0; e < 8; ++e) {
    unsigned short hh = f2bf(v[e]);
    h[e] = (short)hh;
    l[e] = (short)f2bf(v[e] - bf2f(hh));
  }
}
// wave-wide sums via ballots — no DS-pipe ops
__device__ __forceinline__ int waveSum7(int local) {
  int s = 0;
#pragma unroll
  for (int b = 0; b < 7; ++b)
    s += (int)__popcll(__ballot((local >> b) & 1)) << b;
  return s;
}
__device__ __forceinline__ int waveSum2(int local) {
  int s = (int)__popcll(__ballot(local & 1));
  s += (int)__popcll(__ballot((local >> 1) & 1)) << 1;
  return s;
}

// ---------------- K1: transpose + sq + precomputed bf16 hi/lo split -------
__global__ __launch_bounds__(256) void k1_transpose_sq(
    const float* __restrict__ pts, float* __restrict__ xT, float* __restrict__ sqf,
    unsigned short* __restrict__ xh, unsigned short* __restrict__ xl) {
  __shared__ float tile[64 * 65];
  __shared__ double sqp[256];
  const int t = threadIdx.x, blk = blockIdx.x;
  const int b = blk >> 6, n0 = (blk & 63) << 6;
  const float* pb = pts + (size_t)b * CC * NN;
  const int j = t & 63, cg = t >> 6;
  double acc = 0.0;
#pragma unroll
  for (int i = 0; i < 16; ++i) {
    int c = cg * 16 + i;
    float v = pb[(size_t)c * NN + n0 + j];
    tile[c * 65 + j] = v;
    acc += (double)v * (double)v;
  }
  sqp[t] = acc;
  __syncthreads();
  const int c2 = t & 63, jg = t >> 6;
#pragma unroll
  for (int i = 0; i < 16; ++i) {
    int jj = jg * 16 + i;
    float vv = tile[c2 * 65 + jj];
    size_t xoff = ((size_t)b * NN + n0 + jj) * CC + c2;
    xT[xoff] = vv;
    unsigned short hh = f2bf(vv);
    xh[xoff] = hh;
    xl[xoff] = f2bf(vv - bf2f(hh));
  }
  if (t < 64)
    sqf[b * NN + n0 + t] = (float)(sqp[t] + sqp[64 + t] + sqp[128 + t] + sqp[192 + t]);
}

// ---------------- K2b: P = x.w2^T, base = x.(w1-w2)^T ---------------------
__global__ __launch_bounds__(256) void k2b_small_gemm(
    const float* __restrict__ xT, const float* __restrict__ W,
    float* __restrict__ P, float* __restrict__ base) {
  __shared__ float w2T[64 * 65];
  __shared__ float wdT[64 * 65];
  __shared__ float xbuf[4 * 64];
  const int t = threadIdx.x, blk = blockIdx.x;
  const int b = blk >> 6, n0 = (blk & 63) << 6;
#pragma unroll
  for (int i = 0; i < 16; ++i) {
    int e = i * 256 + t, o = e >> 6, c = e & 63;
    w2T[c * 65 + o] = W[o * 128 + 64 + c];
  }
  __syncthreads();
#pragma unroll
  for (int i = 0; i < 16; ++i) {
    int e = i * 256 + t, o = e >> 6, c = e & 63;
    wdT[c * 65 + o] = W[o * 128 + c] - w2T[c * 65 + o];
  }
  __syncthreads();
  const int w = t >> 6, lane = t & 63;
  for (int it = 0; it < 16; ++it) {
    int n = n0 + it * 4 + w;
    xbuf[t] = xT[((size_t)b * NN + n) * CC + lane];
    __syncthreads();
    float accP = 0.f, accB = 0.f;
#pragma unroll
    for (int c = 0; c < 64; ++c) {
      float xc = xbuf[w * 64 + c];
      accP = fmaf(xc, w2T[c * 65 + lane], accP);
      accB = fmaf(xc, wdT[c * 65 + lane], accB);
    }
    size_t off = ((size_t)b * NN + n) * OO + lane;
    P[off] = accP;
    base[off] = accB;
    __syncthreads();
  }
}

// ---------------- K2m: MFMA screen, 1-deep B-prefetch ---------------------
// CHANGE vs R19: software-prefetch next ct's bh/bl/sqc during current ct's
// MFMA+extract (no barriers in loop -> pure load-latency hiding). Math
// order identical -> keys bit-identical. VGPR ~95 < 128.
__global__ __launch_bounds__(256) void k2m_mfma_screen(
    const unsigned short* __restrict__ xhb, const unsigned short* __restrict__ xlb,
    const float* __restrict__ sqb, unsigned short* __restrict__ keys16) {
  __shared__ unsigned short ktile[32 * 512];  // 32KB
  const int t = threadIdx.x, blk = blockIdx.x;
  const int stripe = blk >> 3;   // rows stripe*32..+31
  const int chunk = blk & 7;     // cols chunk*512..+511
  const int wid = t >> 6, l = t & 63;
  const int r0 = stripe * 32;
  const int cbase = chunk * 512 + wid * 128;
  const int i16 = l & 15, kb = l >> 4;

  bf16x8 ah[2][2], al[2][2];
#pragma unroll
  for (int rt = 0; rt < 2; ++rt) {
    size_t rb = (size_t)(r0 + rt * 16 + i16) * CC + kb * 8;
#pragma unroll
    for (int kc = 0; kc < 2; ++kc) {
      ah[rt][kc] = *(const bf16x8*)&xhb[rb + kc * 32];
      al[rt][kc] = *(const bf16x8*)&xlb[rb + kc * 32];
    }
  }
  float srow[2][4];
#pragma unroll
  for (int rt = 0; rt < 2; ++rt)
#pragma unroll
    for (int v = 0; v < 4; ++v)
      srow[rt][v] = sqb[r0 + rt * 16 + kb * 4 + v];

  bf16x8 bh[2], bl[2], nbh[2], nbl[2];
  float sqc, nsqc;
  {
    const int colg = cbase + i16;
    size_t cb = (size_t)colg * CC + kb * 8;
#pragma unroll
    for (int kc = 0; kc < 2; ++kc) {
      bh[kc] = *(const bf16x8*)&xhb[cb + kc * 32];
      bl[kc] = *(const bf16x8*)&xlb[cb + kc * 32];
    }
    sqc = sqb[colg];
  }

  for (int ct = 0; ct < 8; ++ct) {
    if (ct < 7) {  // prefetch next ct's B fragments
      const int ncolg = cbase + (ct + 1) * 16 + i16;
      size_t ncb = (size_t)ncolg * CC + kb * 8;
#pragma unroll
      for (int kc = 0; kc < 2; ++kc) {
        nbh[kc] = *(const bf16x8*)&xhb[ncb + kc * 32];
        nbl[kc] = *(const bf16x8*)&xlb[ncb + kc * 32];
      }
      nsqc = sqb[ncolg];
    }
    const int lcol = wid * 128 + ct * 16 + i16;
#pragma unroll
    for (int rt = 0; rt < 2; ++rt) {
      f32x4 acc = {0.f, 0.f, 0.f, 0.f};
#pragma unroll
      for (int kc = 0; kc < 2; ++kc) {
        acc = __builtin_amdgcn_mfma_f32_16x16x32_bf16(ah[rt][kc], bh[kc], acc, 0, 0, 0);
        acc = __builtin_amdgcn_mfma_f32_16x16x32_bf16(ah[rt][kc], bl[kc], acc, 0, 0, 0);
        acc = __builtin_amdgcn_mfma_f32_16x16x32_bf16(al[rt][kc], bh[kc], acc, 0, 0, 0);
      }
      const int lrow = rt * 16 + kb * 4;
#pragma unroll
      for (int v = 0; v < 4; ++v) {
        float d = 2.0f * acc[v] - srow[rt][v] - sqc;
        ktile[(lrow + v) * 512 + lcol] = (unsigned short)(floatToKey(d) >> 16);
      }
    }
#pragma unroll
    for (int kc = 0; kc < 2; ++kc) { bh[kc] = nbh[kc]; bl[kc] = nbl[kc]; }
    sqc = nsqc;
  }
  __syncthreads();
  // coalesced write-out: 2048 uint4; group of 64 lanes stores one row (1KB)
  uint4* kout = (uint4*)keys16;
#pragma unroll
  for (int i = 0; i < 8; ++i) {
    int e = i * 256 + t;
    int r = e >> 6, c4 = e & 63;
    kout[(size_t)(r0 + r) * (NN / 8) + chunk * 64 + c4] =
        ((const uint4*)ktile)[r * 64 + c4];
  }
}

// ---------------- K2sel: per-wave select, count_ge form -------------------
// CHANGE vs R19: (1) 64 key prefixes pre-extracted ONCE into registers;
// (2) both binary searches use the count_ge formulation: greedy max X with
// #{key >= X} >= 33 == the 33rd-largest value — bit-identical Pv/Pe to the
// path-counting form, but 1 cmp+add per key (no shifts, no R bookkeeping).
__global__ __launch_bounds__(256) void k2sel(
    const unsigned short* __restrict__ keysb, const float* __restrict__ xbp,
    const float* __restrict__ sqb, int* __restrict__ idxout,
    unsigned int* __restrict__ gapb, int* __restrict__ i33out) {
  __shared__ int cnd_gi[4][CAND_MAX];
  __shared__ int cnd_cnt[4];
  __shared__ int sh_list[4][32];
  __shared__ int sh_eq[4][96];
  __shared__ unsigned int sh_kmin[4];
  __shared__ int sh_ngt[4], sh_i33[4], sh_mx[4], sh_cnt[4], sh_ecnt[4];

  const int t = threadIdx.x, blk = blockIdx.x;
  const int v = t >> 6, l = t & 63;
  const int p = blk * 4 + v;  // this wave's row
  const float srf = sqb[p];

  // pre-extract 64 key-prefixes/thread: kk[i] for gi = (i>>3)*512 + l*8 + (i&7)
  unsigned int kk[64];
  {
    const uint4* kp = (const uint4*)(keysb + (size_t)p * NN);
#pragma unroll
    for (int q = 0; q < 8; ++q) {
      uint4 kv = kp[q * 64 + l];
      unsigned int us[4] = {kv.x, kv.y, kv.z, kv.w};
#pragma unroll
      for (int j = 0; j < 4; ++j) {
        kk[q * 8 + 2 * j] = us[j] & 0xffffu;
        kk[q * 8 + 2 * j + 1] = us[j] >> 16;
      }
    }
  }
  if (l == 0) {
    cnd_cnt[v] = 0;
    sh_ngt[v] = 0; sh_kmin[v] = 0xffffffffu; sh_i33[v] = 0x7fffffff;
    sh_mx[v] = -1; sh_cnt[v] = 0; sh_ecnt[v] = 0;
  }
  __syncthreads();

  // ---- phase 2: count_ge binary search for 33rd-largest prefix -----------
  unsigned int Pv = 0;
  for (int bit = 15; bit >= 0; --bit) {
    unsigned int X = Pv | (1u << bit);
    int local = 0;
#pragma unroll
    for (int i = 0; i < 64; ++i) local += (kk[i] >= X) ? 1 : 0;
    int c1 = waveSum7(local);
    if (c1 >= 33) Pv = X;
  }
  const float v33q = keyToFloat(Pv << 16);   // <= s(33) in float order
  const unsigned int thr16 = floatToKey(v33q - EPS2) >> 16;

  // ---- phase 3: collect candidates (prefix >= thr16) ---------------------
#pragma unroll
  for (int i = 0; i < 64; ++i) {
    if (kk[i] >= thr16) {
      int pos = atomicAdd(&cnd_cnt[v], 1);
      if (pos < CAND_MAX) cnd_gi[v][pos] = (i >> 3) * 512 + l * 8 + (i & 7);
    }
  }
  __syncthreads();
  const int M = cnd_cnt[v] < CAND_MAX ? cnd_cnt[v] : CAND_MAX;

  // ---- phase 4: exact fp64-round-once keys (<=3 candidates/lane) ---------
  unsigned int ek[3] = {0u, 0u, 0u};
  int eg[3] = {-1, -1, -1};
  {
    const float4* rp = (const float4*)(xbp + (size_t)p * CC);
#pragma unroll
    for (int c3 = 0; c3 < 3; ++c3) {
      int ci = l + 64 * c3;
      if (ci < M) {
        int gi = cnd_gi[v][ci];
        const float4* mp = (const float4*)&xbp[(size_t)gi * CC];
        double acc = 0.0;
#pragma unroll
        for (int cq = 0; cq < 16; ++cq) {
          float4 rv = rp[cq];
          float4 mv = mp[cq];
          acc += (double)rv.x * (double)mv.x + (double)rv.y * (double)mv.y +
                 (double)rv.z * (double)mv.z + (double)rv.w * (double)mv.w;
        }
        float g = (float)acc;    // fp64 dot rounded once to fp32
        float d = 2.0f * g - srf;
        d = d - sqb[gi];
        ek[c3] = floatToKey(d);
        eg[c3] = gi;
      }
      asm volatile("" ::: "memory");  // no cross-candidate load hoisting
    }
  }

  // ---- phase 5: count_ge binary search for exact K33 ---------------------
  unsigned int Pe = 0;
  for (int bit = 31; bit >= 0; --bit) {
    unsigned int X = Pe | (1u << bit);
    int local = 0;
#pragma unroll
    for (int c3 = 0; c3 < 3; ++c3)
      local += ((eg[c3] >= 0) && (ek[c3] >= X)) ? 1 : 0;
    int c1 = waveSum2(local);
    if (c1 >= 33) Pe = X;
  }
  const unsigned int K33 = Pe;

  int ngt_loc = 0;
  unsigned int kmin_loc = 0xffffffffu;
#pragma unroll
  for (int c3 = 0; c3 < 3; ++c3) {
    if (eg[c3] >= 0) {
      if (ek[c3] > K33) { ngt_loc++; kmin_loc = ek[c3] < kmin_loc ? ek[c3] : kmin_loc; }
      if (ek[c3] == K33) atomicMin(&sh_i33[v], eg[c3]);
    }
  }
  if (ngt_loc) { atomicAdd(&sh_ngt[v], ngt_loc); atomicMin(&sh_kmin[v], kmin_loc); }
  __syncthreads();

  const int ngt = sh_ngt[v];
  const unsigned int K32 = (ngt == 32) ? sh_kmin[v] : K33;
#pragma unroll
  for (int c3 = 0; c3 < 3; ++c3) {
    if (eg[c3] >= 0) {
      if (ek[c3] > K33) { int pos = atomicAdd(&sh_cnt[v], 1); sh_list[v][pos] = eg[c3]; }
      if (ngt == 32 && ek[c3] == K32) atomicMax(&sh_mx[v], eg[c3]);
      if (ngt < 32 && ek[c3] == K33) { int pos = atomicAdd(&sh_ecnt[v], 1); if (pos < 96) sh_eq[v][pos] = eg[c3]; }
    }
  }
  __syncthreads();

  if (l == 0) {
    if (ngt == 32) {
      int target = sh_mx[v], pos = 31;
      for (int q2 = 0; q2 < 32; ++q2) if (sh_list[v][q2] == target) pos = q2;
      int tmp = sh_list[v][31]; sh_list[v][31] = sh_list[v][pos]; sh_list[v][pos] = tmp;
      gapb[p] = __float_as_uint(__fsub_rn(keyToFloat(K32), keyToFloat(K33)));
      i33out[p] = sh_i33[v];
    } else {
      int ec = sh_ecnt[v]; if (ec > 96) ec = 96;
      for (int a = 1; a < ec; ++a) {
        int vv = sh_eq[v][a]; int bp = a - 1;
        while (bp >= 0 && sh_eq[v][bp] > vv) { sh_eq[v][bp + 1] = sh_eq[v][bp]; --bp; }
        sh_eq[v][bp + 1] = vv;
      }
      int need = 32 - ngt;
      for (int a = 0; a < need; ++a) sh_list[v][ngt + a] = sh_eq[v][a];
      gapb[p] = 0x7f800000u;
      i33out[p] = (need < ec) ? sh_eq[v][need] : -1;
    }
  }
  __syncthreads();
  if (l < 32) idxout[(size_t)p * KNN + l] = sh_list[v][l];
}

// ---------------- K2 (fallback, R8-verified): fused screen+select ---------
__global__ __launch_bounds__(256, 2) void k2_gram_select(
    const float* __restrict__ xT, const float* __restrict__ sqf,
    int* __restrict__ idxout, unsigned int* __restrict__ gapb,
    int* __restrict__ i33out) {
  __shared__ __align__(16) float xmT2[2][8192];
  __shared__ float sqm2[2][128];
  __shared__ float xchb[2][256];
  __shared__ int rowcnt[2][4];
  __shared__ int cnd_gi[2][CAND_MAX];
  __shared__ int cnd_cnt[2];
  __shared__ int sh_list[2][32];
  __shared__ int sh_eq[2][96];
  __shared__ unsigned int sh_kmin[2];
  __shared__ int sh_ngt[2], sh_i33[2], sh_mx[2], sh_cnt[2], sh_ecnt[2];

  const int t = threadIdx.x, blk = blockIdx.x;
  const int p0 = blk * 2;
  const int b = p0 >> 12;
  const int row = t >> 7;
  const int col = t & 127;
  const int wid = t >> 6;
  const int sXor = col & 7;
  const float* xbp = xT + (size_t)b * NN * CC;
  const float* sqb = sqf + (size_t)b * NN;

  float4 xa[8], xb4[8];
  {
    const float4* r0 = (const float4*)(xT + (size_t)p0 * CC);
    const float4* r1 = (const float4*)(xT + (size_t)(p0 + 1) * CC);
#pragma unroll
    for (int j = 0; j < 8; ++j) { xa[j] = r0[8 * row + j]; xb4[j] = r1[8 * row + j]; }
  }
  const float srf = sqf[p0 + row];

  unsigned int keys32[32];

  auto stage = [&](int tt, float* xmb, float* sqmb) {
    const int m0s = tt << 7;
#pragma unroll
    for (int q = 0; q < 8; ++q) {
      int e = q * 256 + t;
      int c2 = e >> 4, slot = e & 15;
      const float4* gsrc = (const float4*)xbp + (((size_t)(m0s + c2)) << 4) + (slot ^ (c2 & 7));
      __builtin_amdgcn_global_load_lds(
          (const __attribute__((address_space(1))) void*)gsrc,
          (__attribute__((address_space(3))) void*)(xmb + (size_t)e * 4), 16, 0, 0);
    }
    if (t < 128)
      __builtin_amdgcn_global_load_lds(
          (const __attribute__((address_space(1))) void*)(sqb + m0s + t),
          (__attribute__((address_space(3))) void*)(sqmb + t), 4, 0, 0);
  };

  stage(0, xmT2[0], sqm2[0]);
  float pendA = 0.f, pendB = 0.f, pendSq = 0.f;
#pragma unroll
  for (int tile = 0; tile < 32; ++tile) {
    const int curb = tile & 1;
    asm volatile("s_waitcnt vmcnt(0)" ::: "memory");
    __syncthreads();
    if (tile > 0) {
      float other = xchb[(tile - 1) & 1][t ^ 128];
      float acc = (row == 0) ? (pendA + other) : (other + pendB);
      float dd = 2.0f * acc - srf;
      dd = dd - pendSq;
      keys32[tile - 1] = floatToKey(dd);
    }
    if (tile < 31) stage(tile + 1, xmT2[curb ^ 1], sqm2[curb ^ 1]);
    const float* xm = xmT2[curb];
    float pA = 0.f, pB = 0.f;
#pragma unroll
    for (int j = 0; j < 8; ++j) {
      int slot = (8 * row + j) ^ sXor;
      float4 mv = *(const float4*)&xm[col * 64 + slot * 4];
      pA = fmaf(xa[j].x, mv.x, pA); pA = fmaf(xa[j].y, mv.y, pA);
      pA = fmaf(xa[j].z, mv.z, pA); pA = fmaf(xa[j].w, mv.w, pA);
      pB = fmaf(xb4[j].x, mv.x, pB); pB = fmaf(xb4[j].y, mv.y, pB);
      pB = fmaf(xb4[j].z, mv.z, pB); pB = fmaf(xb4[j].w, mv.w, pB);
    }
    pendA = pA; pendB = pB; pendSq = sqm2[curb][col];
    xchb[tile & 1][t] = (row == 0) ? pB : pA;
  }
  __syncthreads();
  {
    float other = xchb[1][t ^ 128];
    float acc = (row == 0) ? (pendA + other) : (other + pendB);
    float dd = 2.0f * acc - srf;
    dd = dd - pendSq;
    keys32[31] = floatToKey(dd);
  }
  __syncthreads();
  if ((t & 127) == 0) cnd_cnt[row] = 0;

  unsigned int Pv = 0;
  int R = 33;
  for (int bit = 31; bit >= 0; --bit) {
    unsigned int tgt = (Pv >> bit) | 1u;
    int local = 0;
#pragma unroll
    for (int i = 0; i < 32; ++i) local += ((keys32[i] >> bit) == tgt) ? 1 : 0;
#pragma unroll
    for (int off = 32; off > 0; off >>= 1) local += __shfl_down(local, off, 64);
    if ((t & 63) == 0) rowcnt[bit & 1][wid] = local;
    __syncthreads();
    int c1 = rowcnt[bit & 1][row * 2] + rowcnt[bit & 1][row * 2 + 1];
    if (c1 >= R) Pv |= (1u << bit); else R -= c1;
  }
  const unsigned int thr = floatToKey(keyToFloat(Pv) - EPS2);

#pragma unroll
  for (int i = 0; i < 32; ++i) {
    if (keys32[i] >= thr) {
      int pos = atomicAdd(&cnd_cnt[row], 1);
      if (pos < CAND_MAX) cnd_gi[row][pos] = (i << 7) + col;
    }
  }
  __syncthreads();
  const int M = cnd_cnt[row] < CAND_MAX ? cnd_cnt[row] : CAND_MAX;

  {
    const float4* xrp = (const float4*)(xT + (size_t)(p0 + row) * CC);
#pragma unroll
    for (int j = 0; j < 8; ++j) { xa[j] = xrp[j]; xb4[j] = xrp[8 + j]; }
  }
  unsigned int ek0 = 0u, ek1 = 0u;
  int eg0 = -1, eg1 = -1;
  if (col < M) {
    int gi = cnd_gi[row][col];
    const float4* mp = (const float4*)&xbp[(size_t)gi * CC];
    double acc = 0.0;
#pragma unroll
    for (int cq = 0; cq < 8; ++cq) {
      float4 mv = mp[cq];
      acc += (double)xa[cq].x * (double)mv.x + (double)xa[cq].y * (double)mv.y +
             (double)xa[cq].z * (double)mv.z + (double)xa[cq].w * (double)mv.w;
    }
#pragma unroll
    for (int cq = 0; cq < 8; ++cq) {
      float4 mv = mp[8 + cq];
      acc += (double)xb4[cq].x * (double)mv.x + (double)xb4[cq].y * (double)mv.y +
             (double)xb4[cq].z * (double)mv.z + (double)xb4[cq].w * (double)mv.w;
    }
    float g = (float)acc;
    float d = 2.0f * g - srf;
    d = d - sqb[gi];
    ek0 = floatToKey(d);
    eg0 = gi;
  }
  if (col + 128 < M) {
    int gi = cnd_gi[row][col + 128];
    const float4* mp = (const float4*)&xbp[(size_t)gi * CC];
    double acc = 0.0;
#pragma unroll
    for (int cq = 0; cq < 8; ++cq) {
      float4 mv = mp[cq];
      acc += (double)xa[cq].x * (double)mv.x + (double)xa[cq].y * (double)mv.y +
             (double)xa[cq].z * (double)mv.z + (double)xa[cq].w * (double)mv.w;
    }
#pragma unroll
    for (int cq = 0; cq < 8; ++cq) {
      float4 mv = mp[8 + cq];
      acc += (double)xb4[cq].x * (double)mv.x + (double)xb4[cq].y * (double)mv.y +
             (double)xb4[cq].z * (double)mv.z + (double)xb4[cq].w * (double)mv.w;
    }
    float g = (float)acc;
    float d = 2.0f * g - srf;
    d = d - sqb[gi];
    ek1 = floatToKey(d);
    eg1 = gi;
  }

  Pv = 0;
  R = 33;
  for (int bit = 31; bit >= 0; --bit) {
    unsigned int tgt = (Pv >> bit) | 1u;
    int local = ((eg0 >= 0) && ((ek0 >> bit) == tgt)) +
                ((eg1 >= 0) && ((ek1 >> bit) == tgt));
#pragma unroll
    for (int off = 32; off > 0; off >>= 1) local += __shfl_down(local, off, 64);
    if ((t & 63) == 0) rowcnt[bit & 1][wid] = local;
    __syncthreads();
    int c1 = rowcnt[bit & 1][row * 2] + rowcnt[bit & 1][row * 2 + 1];
    if (c1 >= R) Pv |= (1u << bit); else R -= c1;
  }
  const unsigned int K33 = Pv;

  if ((t & 127) == 0) {
    sh_ngt[row] = 0; sh_kmin[row] = 0xffffffffu; sh_i33[row] = 0x7fffffff;
    sh_mx[row] = -1; sh_cnt[row] = 0; sh_ecnt[row] = 0;
  }
  __syncthreads();

  int ngt_loc = 0;
  unsigned int kmin_loc = 0xffffffffu;
  if (eg0 >= 0) {
    if (ek0 > K33) { ngt_loc++; kmin_loc = ek0 < kmin_loc ? ek0 : kmin_loc; }
    if (ek0 == K33) atomicMin(&sh_i33[row], eg0);
  }
  if (eg1 >= 0) {
    if (ek1 > K33) { ngt_loc++; kmin_loc = ek1 < kmin_loc ? ek1 : kmin_loc; }
    if (ek1 == K33) atomicMin(&sh_i33[row], eg1);
  }
  if (ngt_loc) { atomicAdd(&sh_ngt[row], ngt_loc); atomicMin(&sh_kmin[row], kmin_loc); }
  __syncthreads();

  const int ngt = sh_ngt[row];
  const unsigned int K32 = (ngt == 32) ? sh_kmin[row] : K33;
  if (eg0 >= 0) {
    if (ek0 > K33) { int pos = atomicAdd(&sh_cnt[row], 1); sh_list[row][pos] = eg0; }
    if (ngt == 32 && ek0 == K32) atomicMax(&sh_mx[row], eg0);
    if (ngt < 32 && ek0 == K33) { int pos = atomicAdd(&sh_ecnt[row], 1); if (pos < 96) sh_eq[row][pos] = eg0; }
  }
  if (eg1 >= 0) {
    if (ek1 > K33) { int pos = atomicAdd(&sh_cnt[row], 1); sh_list[row][pos] = eg1; }
    if (ngt == 32 && ek1 == K32) atomicMax(&sh_mx[row], eg1);
    if (ngt < 32 && ek1 == K33) { int pos = atomicAdd(&sh_ecnt[row], 1); if (pos < 96) sh_eq[row][pos] = eg1; }
  }
  __syncthreads();

  if ((t & 127) == 0) {
    const int p = p0 + row;
    if (ngt == 32) {
      int target = sh_mx[row], pos = 31;
      for (int q2 = 0; q2 < 32; ++q2) if (sh_list[row][q2] == target) pos = q2;
      int tmp = sh_list[row][31]; sh_list[row][31] = sh_list[row][pos]; sh_list[row][pos] = tmp;
      gapb[p] = __float_as_uint(__fsub_rn(keyToFloat(K32), keyToFloat(K33)));
      i33out[p] = sh_i33[row];
    } else {
      int ec = sh_ecnt[row]; if (ec > 96) ec = 96;
      for (int a = 1; a < ec; ++a) {
        int v = sh_eq[row][a]; int bp = a - 1;
        while (bp >= 0 && sh_eq[row][bp] > v) { sh_eq[row][bp + 1] = sh_eq[row][bp]; --bp; }
        sh_eq[row][bp + 1] = v;
      }
      int need = 32 - ngt;
      for (int a = 0; a < need; ++a) sh_list[row][ngt + a] = sh_eq[row][a];
      gapb[p] = 0x7f800000u;
      i33out[p] = (need < ec) ? sh_eq[row][need] : -1;
    }
  }
  __syncthreads();
  if (t < 64) {
    int rr = t >> 5, k = t & 31;
    idxout[(size_t)(p0 + rr) * KNN + k] = sh_list[rr][k];
  }
}

// ---------------- K2f: flip the globally smallest-positive-gap row --------
__global__ __launch_bounds__(256) void k2f_flip(
    const unsigned int* __restrict__ gapb, const int* __restrict__ i33,
    int* __restrict__ idxout) {
  __shared__ unsigned int sk[256];
  __shared__ int sv[256];
  const int t = threadIdx.x;
  unsigned int best = 0xffffffffu;
  int brow = -1;
  for (int i = t; i < BB * NN; i += 256) {
    unsigned int g = gapb[i];
    if (g < best) { best = g; brow = i; }
  }
  sk[t] = best; sv[t] = brow;
  __syncthreads();
  for (int s = 128; s > 0; s >>= 1) {
    if (t < s && sk[t + s] < sk[t]) { sk[t] = sk[t + s]; sv[t] = sv[t + s]; }
    __syncthreads();
  }
  if (t == 0 && sv[0] >= 0 && sk[0] > 0u && sk[0] < 0x7f800000u) {
    idxout[(size_t)sv[0] * KNN + 31] = i33[sv[0]];
  }
}

// ---------------- K3: gather h=base+P[idx], k-max/min + BN partials -------
__global__ __launch_bounds__(256) void k3_gather_stats(
    const float* __restrict__ Pm, const float* __restrict__ basem,
    const int* __restrict__ idxb, float* __restrict__ hmax,
    float* __restrict__ hmin, float* __restrict__ statsP) {
  const int t = threadIdx.x, blk = blockIdx.x;
  const int w = t >> 6, o = t & 63;
  float s1 = 0.f, s2 = 0.f;
#pragma unroll
  for (int q = 0; q < 4; ++q) {
    int p = blk * 16 + w * 4 + q;
    int b = p >> 12;
    const float* Pb = Pm + (size_t)b * NN * OO;
    float bse = basem[(size_t)p * OO + o];
    const int* ix = idxb + (size_t)p * KNN;
    float mx = -INFINITY, mn = INFINITY;
#pragma unroll 8
    for (int k = 0; k < KNN; ++k) {
      int i = ix[k];
      float h = bse + Pb[(size_t)i * OO + o];
      mx = fmaxf(mx, h);
      mn = fminf(mn, h);
      s1 += h;
      s2 = fmaf(h, h, s2);
    }
    hmax[(size_t)p * OO + o] = mx;
    hmin[(size_t)p * OO + o] = mn;
  }
  __shared__ float red[512];
  red[t] = s1; red[256 + t] = s2;
  __syncthreads();
  if (t < 64) {
    statsP[blk * 128 + t]      = red[t] + red[64 + t] + red[128 + t] + red[192 + t];
    statsP[blk * 128 + 64 + t] = red[256 + t] + red[320 + t] + red[384 + t] + red[448 + t];
  }
}

// ---------------- K4a: parallel partial reduction of statsP ---------------
__global__ __launch_bounds__(256) void k4a_partial(
    const float* __restrict__ statsP, float* __restrict__ part) {
  const int t = threadIdx.x, bi = blockIdx.x;
  const int col = t & 127, rg = t >> 7;  // rg 0/1
  float s = 0.f;
#pragma unroll
  for (int i = 0; i < 4; ++i)
    s += statsP[(bi * 8 + rg * 4 + i) * 128 + col];
  __shared__ float red[256];
  red[t] = s;
  __syncthreads();
  if (t < 128) part[bi * 128 + t] = red[t] + red[128 + t];
}

// ---------------- K4b: finalize BN scale/shift over 128 partials ----------
__global__ __launch_bounds__(256) void k4b_final(
    const float* __restrict__ part, const float* __restrict__ gamma,
    const float* __restrict__ beta, float* __restrict__ scsh) {
  __shared__ float red1[256], red2[256];
  const int t = threadIdx.x;
  const int o = t & 63, c = t >> 6;
  float s1 = 0.f, s2 = 0.f;
  for (int i = c; i < 128; i += 4) {
    s1 += part[i * 128 + o];
    s2 += part[i * 128 + 64 + o];
  }
  red1[t] = s1; red2[t] = s2;
  __syncthreads();
  if (t < 64) {
    s1 = red1[t] + red1[64 + t] + red1[128 + t] + red1[192 + t];
    s2 = red2[t] + red2[64 + t] + red2[128 + t] + red2[192 + t];
    const float inv = 1.0f / 524288.0f;
    float mean = s1 * inv;
    float var = s2 * inv - mean * mean;
    float r = rsqrtf(var + 1e-5f);
    float sc = gamma[t] * r;
    scsh[t] = sc;
    scsh[64 + t] = beta[t] - mean * sc;
  }
}

// ---------------- K5: epilogue: affine+relu on k-max/min, (B,O,N) --------
__global__ __launch_bounds__(256) void k5_epilogue(
    const float* __restrict__ hmax, const float* __restrict__ hmin,
    const float* __restrict__ scsh, float* __restrict__ out) {
  const int id = blockIdx.x * 256 + threadIdx.x;
  const int n = id & 4095, o = (id >> 12) & 63, b = id >> 18;
  float sc = scsh[o], sh = scsh[64 + o];
  size_t hoff = (((size_t)b << 12) + n) * OO + o;
  float H = (sc >= 0.f) ? hmax[hoff] : hmin[hoff];
  float y = sc * H + sh;
  out[id] = y > 0.f ? y : 0.f;
}

extern "C" void kernel_launch(void* const* d_in, const int* in_sizes, int n_in,
                              void* d_out, int out_size, void* d_ws, size_t ws_size,
                              hipStream_t stream) {
  const float* pts   = (const float*)d_in[0];
  const float* W     = (const float*)d_in[1];
  const float* gamma = (const float*)d_in[2];
  const float* beta  = (const float*)d_in[3];
  float* outp = (float*)d_out;
  float* wsf = (float*)d_ws;

  float*          xT    = wsf + XT_OFF;
  float*          sqf   = wsf + SQ_OFF;
  float*          P     = wsf + P_OFF;
  float*          base  = wsf + BASE_OFF;
  float*          hmax  = wsf + HMAX_OFF;
  float*          hmin  = wsf + HMIN_OFF;
  float*          stats = wsf + STATS_OFF;
  float*          scsh  = wsf + SCSH_OFF;
  int*            idx   = (int*)(wsf + IDX_OFF);
  unsigned int*   gapb  = (unsigned int*)(wsf + GAP_OFF);
  int*            i33   = (int*)(wsf + I33_OFF);
  // xh/xl alias hmax/hmin regions (disjoint lifetimes: k1->k2m vs k3->k5)
  unsigned short* xh    = (unsigned short*)(wsf + HMAX_OFF);
  unsigned short* xl    = (unsigned short*)(wsf + HMIN_OFF);
  float*          part  = wsf + P_OFF;   // P region dead after k3

  k1_transpose_sq<<<256, 256, 0, stream>>>(pts, xT, sqf, xh, xl);
  k2b_small_gemm<<<256, 256, 0, stream>>>(xT, W, P, base);

  const int split = (ws_size >= (size_t)(KEYS_OFF + (size_t)NN * NN / 2) * 4u);
  if (split) {
    unsigned short* keys16 = (unsigned short*)(wsf + KEYS_OFF);
    for (int b = 0; b < BB; ++b) {
      k2m_mfma_screen<<<1024, 256, 0, stream>>>(
          xh + (size_t)b * NN * CC, xl + (size_t)b * NN * CC,
          sqf + (size_t)b * NN, keys16);
      k2sel<<<1024, 256, 0, stream>>>(
          keys16, xT + (size_t)b * NN * CC, sqf + (size_t)b * NN,
          idx + (size_t)b * NN * KNN, gapb + (size_t)b * NN,
          i33 + (size_t)b * NN);
    }
  } else {
    k2_gram_select<<<8192, 256, 0, stream>>>(xT, sqf, idx, gapb, i33);
  }
  k2f_flip<<<1, 256, 0, stream>>>(gapb, i33, idx);
  k3_gather_stats<<<1024, 256, 0, stream>>>(P, base, idx, hmax, hmin, stats);
  k4a_partial<<<128, 256, 0, stream>>>(stats, part);
  k4b_final<<<1, 256, 0, stream>>>(part, gamma, beta, scsh);
  k5_epilogue<<<4096, 256, 0, stream>>>(hmax, hmin, scsh, outp);
}